// Round 1
// baseline (1673.844 us; speedup 1.0000x reference)
//
#include <hip/hip_runtime.h>

constexpr int B_ = 2, C_ = 256, H_ = 96, W_ = 96, HW_ = H_ * W_;
constexpr int Hs_ = 48, Ws_ = 48;
constexpr int OMC_ = 216;          // DG*3*KK
constexpr int GNG_ = 32;           // groupnorm groups for C=256 -> 8 ch/group

// ---------------- global average pool over HW per (b,c) ----------------
__global__ __launch_bounds__(256) void k_pool(const float* __restrict__ x, float* __restrict__ pooled) {
    int bc = blockIdx.x;
    const float* p = x + (size_t)bc * HW_;
    float s = 0.f;
    for (int i = threadIdx.x; i < HW_; i += 256) s += p[i];
    __shared__ float red[256];
    red[threadIdx.x] = s; __syncthreads();
    for (int o = 128; o > 0; o >>= 1) {
        if (threadIdx.x < o) red[threadIdx.x] += red[threadIdx.x + o];
        __syncthreads();
    }
    if (threadIdx.x == 0) pooled[bc] = red[0] * (1.f / (float)HW_);
}

// ---------------- atten = 1 + sigmoid(GN(conv1x1(pooled))) ----------------
__global__ __launch_bounds__(256) void k_atten(const float* __restrict__ pooled,
                                               const float* __restrict__ aw, const float* __restrict__ ab,
                                               const float* __restrict__ g1w, const float* __restrict__ g1b,
                                               float* __restrict__ atten) {
    int b = blockIdx.x;
    __shared__ float pl[C_];
    __shared__ float av[C_];
    int o = threadIdx.x;
    pl[o] = pooled[b * C_ + o];
    __syncthreads();
    float s = ab[o];
    const float* wr = aw + (size_t)o * C_;
    for (int c = 0; c < C_; ++c) s += wr[c] * pl[c];
    av[o] = s; __syncthreads();
    int g = o >> 3;
    float m = 0.f;
    for (int i = 0; i < 8; ++i) m += av[g * 8 + i];
    m *= 0.125f;
    float v = 0.f;
    for (int i = 0; i < 8; ++i) { float d = av[g * 8 + i] - m; v += d * d; }
    v *= 0.125f;
    float xn = (s - m) * rsqrtf(v + 1e-5f);
    float gn = xn * g1w[o] + g1b[o];
    atten[b * C_ + o] = 1.f + 1.f / (1.f + expf(-gn));   // store (1+sigmoid) scale
}

// ---------------- bilinear 2x upsample, channel-first ----------------
__global__ __launch_bounds__(256) void k_up(const float* __restrict__ fs, float* __restrict__ up_cf) {
    int bc = blockIdx.x;
    const float* src = fs + (size_t)bc * (Hs_ * Ws_);
    float* dst = up_cf + (size_t)bc * HW_;
    for (int i = threadIdx.x; i < HW_; i += 256) {
        int y = i / W_, x = i - y * W_;
        float syf = fmaxf((y + 0.5f) * 0.5f - 0.5f, 0.f);
        float sxf = fmaxf((x + 0.5f) * 0.5f - 0.5f, 0.f);
        int y0 = (int)syf, x0 = (int)sxf;
        int y1 = min(y0 + 1, Hs_ - 1), x1 = min(x0 + 1, Ws_ - 1);
        float fy = syf - (float)y0, fx = sxf - (float)x0;
        float v00 = src[y0 * Ws_ + x0], v01 = src[y0 * Ws_ + x1];
        float v10 = src[y1 * Ws_ + x0], v11 = src[y1 * Ws_ + x1];
        dst[i] = v00 * (1.f - fy) * (1.f - fx) + v01 * (1.f - fy) * fx
               + v10 * fy * (1.f - fx) + v11 * fy * fx;
    }
}

// ---------------- [B][C][HW] -> [B][HW][C] ----------------
__global__ __launch_bounds__(256) void k_transpose(const float* __restrict__ src, float* __restrict__ dst) {
    __shared__ float t[32][33];
    int b = blockIdx.z;
    int c0 = blockIdx.x * 32, p0 = blockIdx.y * 32;
    const float* s = src + (size_t)b * C_ * HW_;
    float* d = dst + (size_t)b * HW_ * C_;
    int tx = threadIdx.x & 31, ty = threadIdx.x >> 5;   // 32 x 8
    for (int i = 0; i < 32; i += 8)
        t[ty + i][tx] = s[(size_t)(c0 + ty + i) * HW_ + p0 + tx];
    __syncthreads();
    for (int i = 0; i < 32; i += 8)
        d[(size_t)(p0 + ty + i) * C_ + c0 + tx] = t[tx][ty + i];
}

// ---------------- conv1x1 GEMM (M=256) + groupnorm partial stats ----------------
// out[b,m,n] = sum_k A[m,k] * X(k,n) + bias[m];  X rows < K1 from X1 (opt per-row scale),
// rows >= K1 from X2 scaled by scale2.
__global__ __launch_bounds__(256) void k_conv1x1(const float* __restrict__ A, int K, int K1,
                                                 const float* __restrict__ X1, const float* __restrict__ X2,
                                                 const float* __restrict__ rowscale, float scale2,
                                                 const float* __restrict__ bias,
                                                 float* __restrict__ out, float* __restrict__ stats) {
    int m0 = blockIdx.x * 64, n0 = blockIdx.y * 64, b = blockIdx.z;
    int tid = threadIdx.x;
    __shared__ float Al[16][64];
    __shared__ float Xl[16][64];
    __shared__ float gsum[8], gsq[8];
    if (tid < 8) { gsum[tid] = 0.f; gsq[tid] = 0.f; }
    float acc[4][4] = {};
    int tm = tid & 15, tn = tid >> 4;
    int lm = tid >> 2, lk4 = (tid & 3) * 4;       // A-tile load map
    int lkr = tid >> 4, ln4 = (tid & 15) * 4;     // X-tile load map
    for (int k0 = 0; k0 < K; k0 += 16) {
        float4 a = *(const float4*)&A[(size_t)(m0 + lm) * K + k0 + lk4];
        Al[lk4 + 0][lm] = a.x; Al[lk4 + 1][lm] = a.y; Al[lk4 + 2][lm] = a.z; Al[lk4 + 3][lm] = a.w;
        int kg = k0 + lkr;
        const float* src; float sc;
        if (kg < K1) { src = X1 + ((size_t)b * K1 + kg) * HW_ + n0 + ln4; sc = rowscale ? rowscale[b * K1 + kg] : 1.f; }
        else         { src = X2 + ((size_t)b * (K - K1) + (kg - K1)) * HW_ + n0 + ln4; sc = scale2; }
        float4 xv = *(const float4*)src;
        float4 xs; xs.x = xv.x * sc; xs.y = xv.y * sc; xs.z = xv.z * sc; xs.w = xv.w * sc;
        *(float4*)&Xl[lkr][ln4] = xs;
        __syncthreads();
        #pragma unroll
        for (int kk = 0; kk < 16; ++kk) {
            float4 a4 = *(const float4*)&Al[kk][tm * 4];
            float4 b4 = *(const float4*)&Xl[kk][tn * 4];
            acc[0][0] += a4.x * b4.x; acc[0][1] += a4.x * b4.y; acc[0][2] += a4.x * b4.z; acc[0][3] += a4.x * b4.w;
            acc[1][0] += a4.y * b4.x; acc[1][1] += a4.y * b4.y; acc[1][2] += a4.y * b4.z; acc[1][3] += a4.y * b4.w;
            acc[2][0] += a4.z * b4.x; acc[2][1] += a4.z * b4.y; acc[2][2] += a4.z * b4.z; acc[2][3] += a4.z * b4.w;
            acc[3][0] += a4.w * b4.x; acc[3][1] += a4.w * b4.y; acc[3][2] += a4.w * b4.z; acc[3][3] += a4.w * b4.w;
        }
        __syncthreads();
    }
    float lsum = 0.f, lsq = 0.f;
    #pragma unroll
    for (int i = 0; i < 4; ++i) {
        int m = m0 + tm * 4 + i;
        float bi = bias[m];
        #pragma unroll
        for (int j = 0; j < 4; ++j) {
            int n = n0 + tn * 4 + j;
            float v = acc[i][j] + bi;
            out[(size_t)(b * C_ + m) * HW_ + n] = v;
            lsum += v; lsq += v * v;
        }
    }
    atomicAdd(&gsum[tm >> 1], lsum);
    atomicAdd(&gsq[tm >> 1], lsq);
    __syncthreads();
    if (tid < 8) {
        int g = (m0 >> 3) + tid;
        atomicAdd(&stats[(b * GNG_ + g) * 2 + 0], gsum[tid]);
        atomicAdd(&stats[(b * GNG_ + g) * 2 + 1], gsq[tid]);
    }
}

__global__ void k_gnfin(float* stats, float inv_count) {
    int t = threadIdx.x;  // 64 = B*32
    float s = stats[t * 2], q = stats[t * 2 + 1];
    float mean = s * inv_count;
    float var = q * inv_count - mean * mean;
    stats[t * 2] = mean;
    stats[t * 2 + 1] = rsqrtf(var + 1e-5f);
}

__global__ __launch_bounds__(256) void k_gnapply(float* __restrict__ buf, const float* __restrict__ stats,
                                                 const float* __restrict__ w, const float* __restrict__ bgn) {
    int bc = blockIdx.x; int b = bc / C_; int c = bc - b * C_; int g = c >> 3;
    float mean = stats[(b * GNG_ + g) * 2], rstd = stats[(b * GNG_ + g) * 2 + 1];
    float sw = w[c] * rstd;
    float sb = bgn[c] - mean * sw;
    float* p = buf + (size_t)bc * HW_;
    for (int i = threadIdx.x; i < HW_; i += 256) p[i] = p[i] * sw + sb;
}

// ---------------- conv3x3 (pad 1): offset_feat[B,256] -> om[B,216] ----------------
__global__ __launch_bounds__(256) void k_conv3x3(const float* __restrict__ in, const float* __restrict__ w,
                                                 const float* __restrict__ bias, float* __restrict__ out) {
    int tile = blockIdx.x;      // 36 = 6x6 tiles of 16x16
    int ocb = blockIdx.y;       // 9 blocks of 24 oc
    int b = blockIdx.z;
    int ty0 = (tile / 6) * 16, tx0 = (tile % 6) * 16;
    int tid = threadIdx.x;
    __shared__ float t[18][18];
    __shared__ float wl[24][9];
    float acc[24] = {};
    int py = tid >> 4, px = tid & 15;
    for (int ci = 0; ci < C_; ++ci) {
        for (int e = tid; e < 324; e += 256) {
            int yy = e / 18, xx = e - yy * 18;
            int gy = ty0 + yy - 1, gx = tx0 + xx - 1;
            t[yy][xx] = (gy >= 0 && gy < H_ && gx >= 0 && gx < W_)
                        ? in[(size_t)(b * C_ + ci) * HW_ + gy * W_ + gx] : 0.f;
        }
        if (tid < 216) {
            int oc = tid / 9, k = tid - oc * 9;
            wl[oc][k] = w[((size_t)(ocb * 24 + oc) * C_ + ci) * 9 + k];
        }
        __syncthreads();
        float v[9];
        #pragma unroll
        for (int ky = 0; ky < 3; ++ky)
            #pragma unroll
            for (int kx = 0; kx < 3; ++kx) v[ky * 3 + kx] = t[py + ky][px + kx];
        #pragma unroll
        for (int oc = 0; oc < 24; ++oc) {
            float a = acc[oc];
            #pragma unroll
            for (int k = 0; k < 9; ++k) a += v[k] * wl[oc][k];
            acc[oc] = a;
        }
        __syncthreads();
    }
    #pragma unroll
    for (int oc = 0; oc < 24; ++oc) {
        int o = ocb * 24 + oc;
        out[((size_t)b * OMC_ + o) * HW_ + (ty0 + py) * W_ + tx0 + px] = acc[oc] + bias[o];
    }
}

// ---------------- transpose dcn weights: w[o, g*32+c, kh, kw] -> wt[(g*9+k)*32+c][o] ----------------
__global__ __launch_bounds__(256) void k_wt(const float* __restrict__ w, float* __restrict__ wt) {
    int r = blockIdx.x, o = threadIdx.x;
    int c = r & 31, k = (r >> 5) % 9, g = r / 288;
    wt[(size_t)r * 256 + o] = w[((size_t)o * 256 + g * 32 + c) * 9 + k];
}

// ---------------- modulated deformable conv + bias + relu + add feat_arm ----------------
__global__ __launch_bounds__(256) void k_dcn(const float* __restrict__ up_cl, const float* __restrict__ om,
                                             const float* __restrict__ wt, const float* __restrict__ dcnb,
                                             const float* __restrict__ arm, float* __restrict__ outp) {
    int tile = blockIdx.x;     // 576 tiles of 16 consecutive pixels (row-aligned, 96%16==0)
    int b = blockIdx.y;
    int p0 = tile * 16;
    int tid = threadIdx.x;
    __shared__ float Vl[576][16];       // V chunk: 2 groups x 9 k x 32 c  by 16 pixels
    __shared__ float w4s[1152][4];      // per (gk, p): 4 corner weights * mask
    __shared__ short sy0[1152], sx0[1152];

    // phase 0: coords + corner weights for all 72 (g,k) x 16 pixels
    for (int i = tid; i < 1152; i += 256) {
        int pl = i & 15, gk = i >> 4;
        int g = gk / 9, k = gk - g * 9;
        int pix = p0 + pl;
        int hh = pix / W_, ww = pix - hh * W_;
        float oy = om[((size_t)b * OMC_ + g * 18 + 2 * k) * HW_ + pix];
        float ox = om[((size_t)b * OMC_ + g * 18 + 2 * k + 1) * HW_ + pix];
        float mv = om[((size_t)b * OMC_ + 144 + g * 9 + k) * HW_ + pix];
        float m = 1.f / (1.f + expf(-mv));
        float pyf = oy + (float)(hh - 1 + k / 3);
        float pxf = ox + (float)(ww - 1 + k % 3);
        float y0f = floorf(pyf), x0f = floorf(pxf);
        int y0 = (int)y0f, x0 = (int)x0f;
        float fy = pyf - y0f, fx = pxf - x0f;
        float wy0 = (y0 >= 0 && y0 < H_) ? (1.f - fy) : 0.f;
        float wy1 = (y0 + 1 >= 0 && y0 + 1 < H_) ? fy : 0.f;
        float wx0 = (x0 >= 0 && x0 < W_) ? (1.f - fx) : 0.f;
        float wx1 = (x0 + 1 >= 0 && x0 + 1 < W_) ? fx : 0.f;
        w4s[i][0] = wy0 * wx0 * m; w4s[i][1] = wy0 * wx1 * m;
        w4s[i][2] = wy1 * wx0 * m; w4s[i][3] = wy1 * wx1 * m;
        sy0[i] = (short)y0; sx0[i] = (short)x0;
    }
    __syncthreads();

    float acc[4][4] = {};
    int tm = tid >> 2, tn = tid & 3;
    const float* upb = up_cl + (size_t)b * HW_ * C_;
    for (int gc = 0; gc < 4; ++gc) {
        // sampling: fill Vl[576][16]
        int c = tid & 31, pb = (tid >> 5) * 2;
        #pragma unroll 1
        for (int gi = 0; gi < 2; ++gi) {
            int g = gc * 2 + gi;
            #pragma unroll 1
            for (int k = 0; k < 9; ++k) {
                int gk = g * 9 + k;
                #pragma unroll
                for (int pp = 0; pp < 2; ++pp) {
                    int p = pb + pp;
                    int cix = gk * 16 + p;
                    int y0 = sy0[cix], x0 = sx0[cix];
                    int y0c = min(max(y0, 0), H_ - 1), y1c = min(max(y0 + 1, 0), H_ - 1);
                    int x0c = min(max(x0, 0), W_ - 1), x1c = min(max(x0 + 1, 0), W_ - 1);
                    int ch = g * 32 + c;
                    float t00 = upb[(size_t)(y0c * W_ + x0c) * C_ + ch];
                    float t01 = upb[(size_t)(y0c * W_ + x1c) * C_ + ch];
                    float t10 = upb[(size_t)(y1c * W_ + x0c) * C_ + ch];
                    float t11 = upb[(size_t)(y1c * W_ + x1c) * C_ + ch];
                    Vl[(gi * 9 + k) * 32 + c][p] =
                        w4s[cix][0] * t00 + w4s[cix][1] * t01 + w4s[cix][2] * t10 + w4s[cix][3] * t11;
                }
            }
        }
        __syncthreads();
        const float* wtc = wt + (size_t)gc * 576 * 256;
        #pragma unroll 4
        for (int rl = 0; rl < 576; ++rl) {
            float4 a4 = *(const float4*)&wtc[(size_t)rl * 256 + tm * 4];
            float4 v4 = *(const float4*)&Vl[rl][tn * 4];
            acc[0][0] += a4.x * v4.x; acc[0][1] += a4.x * v4.y; acc[0][2] += a4.x * v4.z; acc[0][3] += a4.x * v4.w;
            acc[1][0] += a4.y * v4.x; acc[1][1] += a4.y * v4.y; acc[1][2] += a4.y * v4.z; acc[1][3] += a4.y * v4.w;
            acc[2][0] += a4.z * v4.x; acc[2][1] += a4.z * v4.y; acc[2][2] += a4.z * v4.z; acc[2][3] += a4.z * v4.w;
            acc[3][0] += a4.w * v4.x; acc[3][1] += a4.w * v4.y; acc[3][2] += a4.w * v4.z; acc[3][3] += a4.w * v4.w;
        }
        __syncthreads();
    }
    #pragma unroll
    for (int i = 0; i < 4; ++i) {
        int o = tm * 4 + i;
        float bi = dcnb[o];
        #pragma unroll
        for (int j = 0; j < 4; ++j) {
            int p = p0 + tn * 4 + j;
            float v = acc[i][j] + bi;
            v = fmaxf(v, 0.f) + arm[(size_t)(b * C_ + o) * HW_ + p];
            outp[(size_t)(b * C_ + o) * HW_ + p] = v;
        }
    }
}

extern "C" void kernel_launch(void* const* d_in, const int* in_sizes, int n_in,
                              void* d_out, int out_size, void* d_ws, size_t ws_size,
                              hipStream_t stream) {
    const float* feat_l = (const float*)d_in[0];
    const float* feat_s = (const float*)d_in[1];
    const float* aw  = (const float*)d_in[2];
    const float* ab  = (const float*)d_in[3];
    const float* g1w = (const float*)d_in[4];
    const float* g1b = (const float*)d_in[5];
    const float* cw  = (const float*)d_in[6];
    const float* cb  = (const float*)d_in[7];
    const float* g2w = (const float*)d_in[8];
    const float* g2b = (const float*)d_in[9];
    const float* ow  = (const float*)d_in[10];
    const float* ob  = (const float*)d_in[11];
    const float* gow = (const float*)d_in[12];
    const float* gob = (const float*)d_in[13];
    const float* comw= (const float*)d_in[14];
    const float* comb= (const float*)d_in[15];
    const float* dcnw= (const float*)d_in[16];
    const float* dcnb= (const float*)d_in[17];
    float* out = (float*)d_out;
    float* ws = (float*)d_ws;

    size_t off = 0;
    float* up_cf = ws + off; off += (size_t)B_ * C_ * HW_;
    float* up_cl = ws + off; off += (size_t)B_ * C_ * HW_;
    float* arm   = ws + off; off += (size_t)B_ * C_ * HW_;
    float* offf  = ws + off; off += (size_t)B_ * C_ * HW_;
    float* om    = ws + off; off += (size_t)B_ * OMC_ * HW_;
    float* wt    = ws + off; off += (size_t)2304 * 256;
    float* pooled= ws + off; off += B_ * C_;
    float* atten = ws + off; off += B_ * C_;
    float* stats = ws + off; off += 4 * B_ * GNG_;
    float* stats_arm = stats;
    float* stats_off = stats + 2 * B_ * GNG_;

    hipMemsetAsync(stats, 0, 4 * B_ * GNG_ * sizeof(float), stream);
    k_pool<<<B_ * C_, 256, 0, stream>>>(feat_l, pooled);
    k_atten<<<B_, 256, 0, stream>>>(pooled, aw, ab, g1w, g1b, atten);
    k_up<<<B_ * C_, 256, 0, stream>>>(feat_s, up_cf);
    k_transpose<<<dim3(8, 288, B_), 256, 0, stream>>>(up_cf, up_cl);
    k_conv1x1<<<dim3(4, 144, B_), 256, 0, stream>>>(cw, 256, 256, feat_l, nullptr, atten, 1.f, cb, arm, stats_arm);
    k_gnfin<<<1, 64, 0, stream>>>(stats_arm, 1.f / (8.f * HW_));
    k_gnapply<<<B_ * C_, 256, 0, stream>>>(arm, stats_arm, g2w, g2b);
    k_conv1x1<<<dim3(4, 144, B_), 256, 0, stream>>>(ow, 512, 256, arm, up_cf, nullptr, 2.f, ob, offf, stats_off);
    k_gnfin<<<1, 64, 0, stream>>>(stats_off, 1.f / (8.f * HW_));
    k_gnapply<<<B_ * C_, 256, 0, stream>>>(offf, stats_off, gow, gob);
    k_conv3x3<<<dim3(36, 9, B_), 256, 0, stream>>>(offf, comw, comb, om);
    k_wt<<<2304, 256, 0, stream>>>(dcnw, wt);
    k_dcn<<<dim3(576, B_), 256, 0, stream>>>(up_cl, om, wt, dcnb, arm, out);
}

// Round 3
// 1067.935 us; speedup vs baseline: 1.5674x; 1.5674x over previous
//
#include <hip/hip_runtime.h>

constexpr int B_ = 2, C_ = 256, H_ = 96, W_ = 96, HW_ = H_ * W_;
constexpr int Hs_ = 48, Ws_ = 48;
constexpr int OMC_ = 216;          // DG*3*KK
constexpr int GNG_ = 32;           // groupnorm groups for C=256 -> 8 ch/group

typedef __attribute__((ext_vector_type(8))) short short8;
typedef __attribute__((ext_vector_type(16))) float f32x16;

// ---------------- global average pool over HW per (b,c) ----------------
__global__ __launch_bounds__(256) void k_pool(const float* __restrict__ x, float* __restrict__ pooled) {
    int bc = blockIdx.x;
    const float* p = x + (size_t)bc * HW_;
    float s = 0.f;
    for (int i = threadIdx.x; i < HW_; i += 256) s += p[i];
    __shared__ float red[256];
    red[threadIdx.x] = s; __syncthreads();
    for (int o = 128; o > 0; o >>= 1) {
        if (threadIdx.x < o) red[threadIdx.x] += red[threadIdx.x + o];
        __syncthreads();
    }
    if (threadIdx.x == 0) pooled[bc] = red[0] * (1.f / (float)HW_);
}

// ---------------- atten = 1 + sigmoid(GN(conv1x1(pooled))) ----------------
__global__ __launch_bounds__(256) void k_atten(const float* __restrict__ pooled,
                                               const float* __restrict__ aw, const float* __restrict__ ab,
                                               const float* __restrict__ g1w, const float* __restrict__ g1b,
                                               float* __restrict__ atten) {
    int b = blockIdx.x;
    __shared__ float pl[C_];
    __shared__ float av[C_];
    int o = threadIdx.x;
    pl[o] = pooled[b * C_ + o];
    __syncthreads();
    float s = ab[o];
    const float* wr = aw + (size_t)o * C_;
    for (int c = 0; c < C_; ++c) s += wr[c] * pl[c];
    av[o] = s; __syncthreads();
    int g = o >> 3;
    float m = 0.f;
    for (int i = 0; i < 8; ++i) m += av[g * 8 + i];
    m *= 0.125f;
    float v = 0.f;
    for (int i = 0; i < 8; ++i) { float d = av[g * 8 + i] - m; v += d * d; }
    v *= 0.125f;
    float xn = (s - m) * rsqrtf(v + 1e-5f);
    float gn = xn * g1w[o] + g1b[o];
    atten[b * C_ + o] = 1.f + 1.f / (1.f + expf(-gn));   // store (1+sigmoid) scale
}

// ---------------- bilinear 2x upsample, channel-first ----------------
__global__ __launch_bounds__(256) void k_up(const float* __restrict__ fs, float* __restrict__ up_cf) {
    int bc = blockIdx.x;
    const float* src = fs + (size_t)bc * (Hs_ * Ws_);
    float* dst = up_cf + (size_t)bc * HW_;
    for (int i = threadIdx.x; i < HW_; i += 256) {
        int y = i / W_, x = i - y * W_;
        float syf = fmaxf((y + 0.5f) * 0.5f - 0.5f, 0.f);
        float sxf = fmaxf((x + 0.5f) * 0.5f - 0.5f, 0.f);
        int y0 = (int)syf, x0 = (int)sxf;
        int y1 = min(y0 + 1, Hs_ - 1), x1 = min(x0 + 1, Ws_ - 1);
        float fy = syf - (float)y0, fx = sxf - (float)x0;
        float v00 = src[y0 * Ws_ + x0], v01 = src[y0 * Ws_ + x1];
        float v10 = src[y1 * Ws_ + x0], v11 = src[y1 * Ws_ + x1];
        dst[i] = v00 * (1.f - fy) * (1.f - fx) + v01 * (1.f - fy) * fx
               + v10 * fy * (1.f - fx) + v11 * fy * fx;
    }
}

// ---------------- [B][C][HW] -> [B][HW][C] ----------------
__global__ __launch_bounds__(256) void k_transpose(const float* __restrict__ src, float* __restrict__ dst) {
    __shared__ float t[32][33];
    int b = blockIdx.z;
    int c0 = blockIdx.x * 32, p0 = blockIdx.y * 32;
    const float* s = src + (size_t)b * C_ * HW_;
    float* d = dst + (size_t)b * HW_ * C_;
    int tx = threadIdx.x & 31, ty = threadIdx.x >> 5;   // 32 x 8
    for (int i = 0; i < 32; i += 8)
        t[ty + i][tx] = s[(size_t)(c0 + ty + i) * HW_ + p0 + tx];
    __syncthreads();
    for (int i = 0; i < 32; i += 8)
        d[(size_t)(p0 + ty + i) * C_ + c0 + tx] = t[tx][ty + i];
}

// ---------------- conv1x1 GEMM (M=256) + groupnorm partial stats ----------------
__global__ __launch_bounds__(256) void k_conv1x1(const float* __restrict__ A, int K, int K1,
                                                 const float* __restrict__ X1, const float* __restrict__ X2,
                                                 const float* __restrict__ rowscale, float scale2,
                                                 const float* __restrict__ bias,
                                                 float* __restrict__ out, float* __restrict__ stats) {
    int m0 = blockIdx.x * 64, n0 = blockIdx.y * 64, b = blockIdx.z;
    int tid = threadIdx.x;
    __shared__ float Al[16][64];
    __shared__ float Xl[16][64];
    __shared__ float gsum[8], gsq[8];
    if (tid < 8) { gsum[tid] = 0.f; gsq[tid] = 0.f; }
    float acc[4][4] = {};
    int tm = tid & 15, tn = tid >> 4;
    int lm = tid >> 2, lk4 = (tid & 3) * 4;       // A-tile load map
    int lkr = tid >> 4, ln4 = (tid & 15) * 4;     // X-tile load map
    for (int k0 = 0; k0 < K; k0 += 16) {
        float4 a = *(const float4*)&A[(size_t)(m0 + lm) * K + k0 + lk4];
        Al[lk4 + 0][lm] = a.x; Al[lk4 + 1][lm] = a.y; Al[lk4 + 2][lm] = a.z; Al[lk4 + 3][lm] = a.w;
        int kg = k0 + lkr;
        const float* src; float sc;
        if (kg < K1) { src = X1 + ((size_t)b * K1 + kg) * HW_ + n0 + ln4; sc = rowscale ? rowscale[b * K1 + kg] : 1.f; }
        else         { src = X2 + ((size_t)b * (K - K1) + (kg - K1)) * HW_ + n0 + ln4; sc = scale2; }
        float4 xv = *(const float4*)src;
        float4 xs; xs.x = xv.x * sc; xs.y = xv.y * sc; xs.z = xv.z * sc; xs.w = xv.w * sc;
        *(float4*)&Xl[lkr][ln4] = xs;
        __syncthreads();
        #pragma unroll
        for (int kk = 0; kk < 16; ++kk) {
            float4 a4 = *(const float4*)&Al[kk][tm * 4];
            float4 b4 = *(const float4*)&Xl[kk][tn * 4];
            acc[0][0] += a4.x * b4.x; acc[0][1] += a4.x * b4.y; acc[0][2] += a4.x * b4.z; acc[0][3] += a4.x * b4.w;
            acc[1][0] += a4.y * b4.x; acc[1][1] += a4.y * b4.y; acc[1][2] += a4.y * b4.z; acc[1][3] += a4.y * b4.w;
            acc[2][0] += a4.z * b4.x; acc[2][1] += a4.z * b4.y; acc[2][2] += a4.z * b4.z; acc[2][3] += a4.z * b4.w;
            acc[3][0] += a4.w * b4.x; acc[3][1] += a4.w * b4.y; acc[3][2] += a4.w * b4.z; acc[3][3] += a4.w * b4.w;
        }
        __syncthreads();
    }
    float lsum = 0.f, lsq = 0.f;
    #pragma unroll
    for (int i = 0; i < 4; ++i) {
        int m = m0 + tm * 4 + i;
        float bi = bias[m];
        #pragma unroll
        for (int j = 0; j < 4; ++j) {
            int n = n0 + tn * 4 + j;
            float v = acc[i][j] + bi;
            out[(size_t)(b * C_ + m) * HW_ + n] = v;
            lsum += v; lsq += v * v;
        }
    }
    atomicAdd(&gsum[tm >> 1], lsum);
    atomicAdd(&gsq[tm >> 1], lsq);
    __syncthreads();
    if (tid < 8) {
        int g = (m0 >> 3) + tid;
        atomicAdd(&stats[(b * GNG_ + g) * 2 + 0], gsum[tid]);
        atomicAdd(&stats[(b * GNG_ + g) * 2 + 1], gsq[tid]);
    }
}

__global__ void k_gnfin(float* stats, float inv_count) {
    int t = threadIdx.x;  // 64 = B*32
    float s = stats[t * 2], q = stats[t * 2 + 1];
    float mean = s * inv_count;
    float var = q * inv_count - mean * mean;
    stats[t * 2] = mean;
    stats[t * 2 + 1] = rsqrtf(var + 1e-5f);
}

__global__ __launch_bounds__(256) void k_gnapply(float* __restrict__ buf, const float* __restrict__ stats,
                                                 const float* __restrict__ w, const float* __restrict__ bgn) {
    int bc = blockIdx.x; int b = bc / C_; int c = bc - b * C_; int g = c >> 3;
    float mean = stats[(b * GNG_ + g) * 2], rstd = stats[(b * GNG_ + g) * 2 + 1];
    float sw = w[c] * rstd;
    float sb = bgn[c] - mean * sw;
    float* p = buf + (size_t)bc * HW_;
    for (int i = threadIdx.x; i < HW_; i += 256) p[i] = p[i] * sw + sb;
}

// ------- bf16 hi/lo split helpers (RTNE) -------
__device__ __forceinline__ void bf16split(float v, ushort& h, ushort& l) {
    unsigned u = __float_as_uint(v);
    unsigned hr = (u + 0x7FFFu + ((u >> 16) & 1u)) >> 16;
    float hf = __uint_as_float(hr << 16);
    unsigned u2 = __float_as_uint(v - hf);
    unsigned lr_ = (u2 + 0x7FFFu + ((u2 >> 16) & 1u)) >> 16;
    h = (ushort)hr; l = (ushort)lr_;
}

// ------- weight prep: comw[216][256][3][3] -> awt_{h,l}[72][256][32] (tap-major k-steps, m-padded) -------
__global__ __launch_bounds__(256) void k_prepw(const float* __restrict__ w,
                                               ushort* __restrict__ ah, ushort* __restrict__ al) {
    int q = blockIdx.x;        // 72 k-steps: tap = q>>3, cb = q&7
    int m = threadIdx.x;       // 256 rows (pad >=216 with zeros)
    int tap = q >> 3, cb = q & 7;
    ushort hbuf[32], lbuf[32];
    #pragma unroll
    for (int kk = 0; kk < 32; ++kk) {
        float v = 0.f;
        if (m < OMC_) v = w[((size_t)m * 256 + cb * 32 + kk) * 9 + tap];
        bf16split(v, hbuf[kk], lbuf[kk]);
    }
    size_t base = ((size_t)q * 256 + m) * 32;
    #pragma unroll
    for (int i = 0; i < 4; ++i) {
        ((uint4*)(ah + base))[i] = ((const uint4*)hbuf)[i];
        ((uint4*)(al + base))[i] = ((const uint4*)lbuf)[i];
    }
}

// ------- activation prep: offf[b][256][9216] -> xh/xl [b][8][9216][32] (32-ch chunk last) -------
__global__ __launch_bounds__(256) void k_prepx(const float* __restrict__ src,
                                               ushort* __restrict__ xhh, ushort* __restrict__ xll) {
    int pt = blockIdx.x;       // 144 tiles of 64 px
    int cb = blockIdx.y;       // 8
    int b  = blockIdx.z;       // 2
    int p0 = pt * 64;
    __shared__ __align__(16) ushort th[32][72];
    __shared__ __align__(16) ushort tl[32][72];
    int t = threadIdx.x;
    int c = t >> 3, j8 = (t & 7) * 8;
    const float* srow = src + ((size_t)b * 256 + cb * 32 + c) * HW_ + p0 + j8;
    float4 v0 = *(const float4*)srow;
    float4 v1 = *(const float4*)(srow + 4);
    float vv[8] = {v0.x, v0.y, v0.z, v0.w, v1.x, v1.y, v1.z, v1.w};
    ushort hv[8], lv[8];
    #pragma unroll
    for (int i = 0; i < 8; ++i) bf16split(vv[i], hv[i], lv[i]);
    *(uint4*)&th[c][j8] = *(const uint4*)hv;
    *(uint4*)&tl[c][j8] = *(const uint4*)lv;
    __syncthreads();
    int p = t >> 2, ch = (t & 3) * 8;
    ushort oh[8], ol[8];
    #pragma unroll
    for (int i = 0; i < 8; ++i) { oh[i] = th[ch + i][p]; ol[i] = tl[ch + i][p]; }
    size_t obase = (((size_t)(b * 8 + cb)) * HW_ + p0 + p) * 32 + ch;
    *(uint4*)(xhh + obase) = *(const uint4*)oh;
    *(uint4*)(xll + obase) = *(const uint4*)ol;
}

// ------- conv3x3 via MFMA (split-bf16, implicit im2col). K split in 2 across blockIdx.y -------
// out partial buffers om1 (ks=0, includes bias) / om2 (ks=1); layout [b][216][9216]
__global__ __launch_bounds__(256) void k_conv3x3m(const ushort* __restrict__ awt_h, const ushort* __restrict__ awt_l,
                                                  const ushort* __restrict__ xh, const ushort* __restrict__ xl,
                                                  const float* __restrict__ bias,
                                                  float* __restrict__ om1, float* __restrict__ om2) {
    int nb = blockIdx.x;        // 144 pixel tiles of 64
    int ks = blockIdx.y;        // K-split half
    int b  = blockIdx.z;
    int n0 = nb * 64;
    __shared__ __align__(16) ushort Ah[256 * 32];
    __shared__ __align__(16) ushort Al[256 * 32];
    __shared__ __align__(16) ushort Bh[64 * 32];
    __shared__ __align__(16) ushort Bl[64 * 32];
    int tid = threadIdx.x;
    int lane = tid & 63, wv = tid >> 6;
    int mh = (wv >> 1) * 128;   // wave m-base (4 frags of 32)
    int nq = (wv & 1) * 32;     // wave n-base (1 frag of 32)
    int lr = lane & 31;
    int kg = lane >> 5;

    f32x16 acc[4] = {};

    // B staging map (per thread)
    int sn = tid >> 2, sch = tid & 3;
    int sp = n0 + sn;
    int spy = sp / W_, spx = sp - spy * W_;

    for (int q = ks * 36; q < ks * 36 + 36; ++q) {
        int tap = q >> 3, cb = q & 7;
        int dy = tap / 3 - 1, dx = tap % 3 - 1;
        // ---- stage A (linear copy with chunk swizzle) ----
        const uint4* gah = (const uint4*)(awt_h + (size_t)q * 8192);
        const uint4* gal = (const uint4*)(awt_l + (size_t)q * 8192);
        uint4* sah = (uint4*)Ah; uint4* sal = (uint4*)Al;
        #pragma unroll
        for (int i = 0; i < 4; ++i) {
            int ci = i * 256 + tid;
            int m = ci >> 2, c4 = ci & 3;
            int sw = c4 ^ ((m >> 1) & 3);
            sah[m * 4 + sw] = gah[ci];
            sal[m * 4 + sw] = gal[ci];
        }
        // ---- stage B (shifted, bounds-checked) ----
        {
            int y = spy + dy, x = spx + dx;
            uint4 vh = {0u, 0u, 0u, 0u}, vl = {0u, 0u, 0u, 0u};
            if ((unsigned)y < (unsigned)H_ && (unsigned)x < (unsigned)W_) {
                size_t sidx = (((size_t)(b * 8 + cb)) * HW_ + y * W_ + x) * 32 + sch * 8;
                vh = *(const uint4*)(xh + sidx);
                vl = *(const uint4*)(xl + sidx);
            }
            int sw = sch ^ ((sn >> 1) & 3);
            ((uint4*)Bh)[sn * 4 + sw] = vh;
            ((uint4*)Bl)[sn * 4 + sw] = vl;
        }
        __syncthreads();
        // ---- compute: 2 k-subs of 16 ----
        #pragma unroll
        for (int s = 0; s < 2; ++s) {
            int chnk = 2 * s + kg;
            int nn = nq + lr;
            int bby = nn * 64 + ((chnk ^ ((nn >> 1) & 3)) << 4);
            short8 bh = *(const short8*)((const char*)Bh + bby);
            short8 bl = *(const short8*)((const char*)Bl + bby);
            #pragma unroll
            for (int f = 0; f < 4; ++f) {
                int row = mh + f * 32 + lr;
                int aby = row * 64 + ((chnk ^ ((row >> 1) & 3)) << 4);
                short8 a_h = *(const short8*)((const char*)Ah + aby);
                short8 a_l = *(const short8*)((const char*)Al + aby);
                acc[f] = __builtin_amdgcn_mfma_f32_32x32x16_bf16(a_h, bh, acc[f], 0, 0, 0);
                acc[f] = __builtin_amdgcn_mfma_f32_32x32x16_bf16(a_h, bl, acc[f], 0, 0, 0);
                acc[f] = __builtin_amdgcn_mfma_f32_32x32x16_bf16(a_l, bh, acc[f], 0, 0, 0);
            }
        }
        __syncthreads();
    }
    // ---- epilogue ----
    float* outp = (ks ? om2 : om1) + (size_t)b * OMC_ * HW_;
    int pix = n0 + nq + lr;
    #pragma unroll
    for (int f = 0; f < 4; ++f) {
        #pragma unroll
        for (int r = 0; r < 16; ++r) {
            int m = mh + f * 32 + (r & 3) + 8 * (r >> 2) + 4 * kg;
            if (m < OMC_) {
                float v = acc[f][r] + (ks ? 0.f : bias[m]);
                outp[(size_t)m * HW_ + pix] = v;
            }
        }
    }
}

// ---------------- transpose dcn weights: w[o, g*32+c, kh, kw] -> wt[(g*9+k)*32+c][o] ----------------
__global__ __launch_bounds__(256) void k_wt(const float* __restrict__ w, float* __restrict__ wt) {
    int r = blockIdx.x, o = threadIdx.x;
    int c = r & 31, k = (r >> 5) % 9, g = r / 288;
    wt[(size_t)r * 256 + o] = w[((size_t)o * 256 + g * 32 + c) * 9 + k];
}

// ---------------- modulated deformable conv + bias + relu + add feat_arm ----------------
__global__ __launch_bounds__(256) void k_dcn(const float* __restrict__ up_cl,
                                             const float* __restrict__ om1, const float* __restrict__ om2,
                                             const float* __restrict__ wt, const float* __restrict__ dcnb,
                                             const float* __restrict__ arm, float* __restrict__ outp) {
    int tile = blockIdx.x;     // 576 tiles of 16 consecutive pixels
    int b = blockIdx.y;
    int p0 = tile * 16;
    int tid = threadIdx.x;
    __shared__ float Vl[576][16];
    __shared__ float w4s[1152][4];
    __shared__ short sy0[1152], sx0[1152];

    for (int i = tid; i < 1152; i += 256) {
        int pl = i & 15, gk = i >> 4;
        int g = gk / 9, k = gk - g * 9;
        int pix = p0 + pl;
        int hh = pix / W_, ww = pix - hh * W_;
        size_t i_oy = ((size_t)b * OMC_ + g * 18 + 2 * k) * HW_ + pix;
        size_t i_ox = ((size_t)b * OMC_ + g * 18 + 2 * k + 1) * HW_ + pix;
        size_t i_mv = ((size_t)b * OMC_ + 144 + g * 9 + k) * HW_ + pix;
        float oy = om1[i_oy] + om2[i_oy];
        float ox = om1[i_ox] + om2[i_ox];
        float mv = om1[i_mv] + om2[i_mv];
        float m = 1.f / (1.f + expf(-mv));
        float pyf = oy + (float)(hh - 1 + k / 3);
        float pxf = ox + (float)(ww - 1 + k % 3);
        float y0f = floorf(pyf), x0f = floorf(pxf);
        int y0 = (int)y0f, x0 = (int)x0f;
        float fy = pyf - y0f, fx = pxf - x0f;
        float wy0 = (y0 >= 0 && y0 < H_) ? (1.f - fy) : 0.f;
        float wy1 = (y0 + 1 >= 0 && y0 + 1 < H_) ? fy : 0.f;
        float wx0 = (x0 >= 0 && x0 < W_) ? (1.f - fx) : 0.f;
        float wx1 = (x0 + 1 >= 0 && x0 + 1 < W_) ? fx : 0.f;
        w4s[i][0] = wy0 * wx0 * m; w4s[i][1] = wy0 * wx1 * m;
        w4s[i][2] = wy1 * wx0 * m; w4s[i][3] = wy1 * wx1 * m;
        sy0[i] = (short)y0; sx0[i] = (short)x0;
    }
    __syncthreads();

    float acc[4][4] = {};
    int tm = tid >> 2, tn = tid & 3;
    const float* upb = up_cl + (size_t)b * HW_ * C_;
    for (int gc = 0; gc < 4; ++gc) {
        int c = tid & 31, pb = (tid >> 5) * 2;
        #pragma unroll 1
        for (int gi = 0; gi < 2; ++gi) {
            int g = gc * 2 + gi;
            #pragma unroll 1
            for (int k = 0; k < 9; ++k) {
                int gk = g * 9 + k;
                #pragma unroll
                for (int pp = 0; pp < 2; ++pp) {
                    int p = pb + pp;
                    int cix = gk * 16 + p;
                    int y0 = sy0[cix], x0 = sx0[cix];
                    int y0c = min(max(y0, 0), H_ - 1), y1c = min(max(y0 + 1, 0), H_ - 1);
                    int x0c = min(max(x0, 0), W_ - 1), x1c = min(max(x0 + 1, 0), W_ - 1);
                    int ch = g * 32 + c;
                    float t00 = upb[(size_t)(y0c * W_ + x0c) * C_ + ch];
                    float t01 = upb[(size_t)(y0c * W_ + x1c) * C_ + ch];
                    float t10 = upb[(size_t)(y1c * W_ + x0c) * C_ + ch];
                    float t11 = upb[(size_t)(y1c * W_ + x1c) * C_ + ch];
                    Vl[(gi * 9 + k) * 32 + c][p] =
                        w4s[cix][0] * t00 + w4s[cix][1] * t01 + w4s[cix][2] * t10 + w4s[cix][3] * t11;
                }
            }
        }
        __syncthreads();
        const float* wtc = wt + (size_t)gc * 576 * 256;
        #pragma unroll 4
        for (int rl = 0; rl < 576; ++rl) {
            float4 a4 = *(const float4*)&wtc[(size_t)rl * 256 + tm * 4];
            float4 v4 = *(const float4*)&Vl[rl][tn * 4];
            acc[0][0] += a4.x * v4.x; acc[0][1] += a4.x * v4.y; acc[0][2] += a4.x * v4.z; acc[0][3] += a4.x * v4.w;
            acc[1][0] += a4.y * v4.x; acc[1][1] += a4.y * v4.y; acc[1][2] += a4.y * v4.z; acc[1][3] += a4.y * v4.w;
            acc[2][0] += a4.z * v4.x; acc[2][1] += a4.z * v4.y; acc[2][2] += a4.z * v4.z; acc[2][3] += a4.z * v4.w;
            acc[3][0] += a4.w * v4.x; acc[3][1] += a4.w * v4.y; acc[3][2] += a4.w * v4.z; acc[3][3] += a4.w * v4.w;
        }
        __syncthreads();
    }
    #pragma unroll
    for (int i = 0; i < 4; ++i) {
        int o = tm * 4 + i;
        float bi = dcnb[o];
        #pragma unroll
        for (int j = 0; j < 4; ++j) {
            int p = p0 + tn * 4 + j;
            float v = acc[i][j] + bi;
            v = fmaxf(v, 0.f) + arm[(size_t)(b * C_ + o) * HW_ + p];
            outp[(size_t)(b * C_ + o) * HW_ + p] = v;
        }
    }
}

extern "C" void kernel_launch(void* const* d_in, const int* in_sizes, int n_in,
                              void* d_out, int out_size, void* d_ws, size_t ws_size,
                              hipStream_t stream) {
    const float* feat_l = (const float*)d_in[0];
    const float* feat_s = (const float*)d_in[1];
    const float* aw  = (const float*)d_in[2];
    const float* ab  = (const float*)d_in[3];
    const float* g1w = (const float*)d_in[4];
    const float* g1b = (const float*)d_in[5];
    const float* cw  = (const float*)d_in[6];
    const float* cb  = (const float*)d_in[7];
    const float* g2w = (const float*)d_in[8];
    const float* g2b = (const float*)d_in[9];
    const float* ow  = (const float*)d_in[10];
    const float* ob  = (const float*)d_in[11];
    const float* gow = (const float*)d_in[12];
    const float* gob = (const float*)d_in[13];
    const float* comw= (const float*)d_in[14];
    const float* comb= (const float*)d_in[15];
    const float* dcnw= (const float*)d_in[16];
    const float* dcnb= (const float*)d_in[17];
    float* out = (float*)d_out;
    float* ws = (float*)d_ws;

    // Workspace plan (with stream-order-safe aliasing, ~97 MB):
    //   up_cf  : dead after k_conv1x1#2  -> reused as om2 (written by k_conv3x3m)
    //   offf   : dead after k_prepx      -> reused as om1 (written by k_conv3x3m)
    //   awth/awtl: dead after k_conv3x3m -> region reused as wt (written by k_wt)
    size_t off = 0;
    float* up_cf = ws + off; off += (size_t)B_ * C_ * HW_;
    float* up_cl = ws + off; off += (size_t)B_ * C_ * HW_;
    float* arm   = ws + off; off += (size_t)B_ * C_ * HW_;
    float* offf  = ws + off; off += (size_t)B_ * C_ * HW_;
    float* wt    = ws + off; off += (size_t)2304 * 256;          // 589824 floats
    ushort* awth = (ushort*)wt;                                   // 589824 ushorts
    ushort* awtl = awth + (size_t)72 * 256 * 32;                  // 589824 ushorts (wt region total = exact fit)
    ushort* xh   = (ushort*)(ws + off); off += (size_t)B_ * 8 * HW_ * 32 / 2;
    ushort* xl   = (ushort*)(ws + off); off += (size_t)B_ * 8 * HW_ * 32 / 2;
    float* pooled= ws + off; off += B_ * C_;
    float* atten = ws + off; off += B_ * C_;
    float* stats = ws + off; off += 4 * B_ * GNG_;
    float* stats_arm = stats;
    float* stats_off = stats + 2 * B_ * GNG_;
    float* om1 = offf;    // alias: offf dead after k_prepx
    float* om2 = up_cf;   // alias: up_cf dead after second conv1x1

    hipMemsetAsync(stats, 0, 4 * B_ * GNG_ * sizeof(float), stream);
    k_pool<<<B_ * C_, 256, 0, stream>>>(feat_l, pooled);
    k_atten<<<B_, 256, 0, stream>>>(pooled, aw, ab, g1w, g1b, atten);
    k_up<<<B_ * C_, 256, 0, stream>>>(feat_s, up_cf);
    k_transpose<<<dim3(8, 288, B_), 256, 0, stream>>>(up_cf, up_cl);
    k_conv1x1<<<dim3(4, 144, B_), 256, 0, stream>>>(cw, 256, 256, feat_l, nullptr, atten, 1.f, cb, arm, stats_arm);
    k_gnfin<<<1, 64, 0, stream>>>(stats_arm, 1.f / (8.f * HW_));
    k_gnapply<<<B_ * C_, 256, 0, stream>>>(arm, stats_arm, g2w, g2b);
    k_conv1x1<<<dim3(4, 144, B_), 256, 0, stream>>>(ow, 512, 256, arm, up_cf, nullptr, 2.f, ob, offf, stats_off);
    k_gnfin<<<1, 64, 0, stream>>>(stats_off, 1.f / (8.f * HW_));
    k_gnapply<<<B_ * C_, 256, 0, stream>>>(offf, stats_off, gow, gob);
    k_prepw<<<72, 256, 0, stream>>>(comw, awth, awtl);
    k_prepx<<<dim3(144, 8, B_), 256, 0, stream>>>(offf, xh, xl);
    k_conv3x3m<<<dim3(144, 2, B_), 256, 0, stream>>>(awth, awtl, xh, xl, comb, om1, om2);
    k_wt<<<2304, 256, 0, stream>>>(dcnw, wt);
    k_dcn<<<dim3(576, B_), 256, 0, stream>>>(up_cl, om1, om2, wt, dcnb, arm, out);
}

// Round 8
// 560.976 us; speedup vs baseline: 2.9838x; 1.9037x over previous
//
#include <hip/hip_runtime.h>

constexpr int B_ = 2, C_ = 256, H_ = 96, W_ = 96, HW_ = H_ * W_;
constexpr int Hs_ = 48, Ws_ = 48;
constexpr int OMC_ = 216;          // DG*3*KK
constexpr int GNG_ = 32;           // groupnorm groups for C=256 -> 8 ch/group

typedef __attribute__((ext_vector_type(8))) short short8;
typedef __attribute__((ext_vector_type(16))) float f32x16;

// ---------------- global average pool over HW per (b,c) ----------------
__global__ __launch_bounds__(256) void k_pool(const float* __restrict__ x, float* __restrict__ pooled) {
    int bc = blockIdx.x;
    const float* p = x + (size_t)bc * HW_;
    float s = 0.f;
    for (int i = threadIdx.x; i < HW_; i += 256) s += p[i];
    __shared__ float red[256];
    red[threadIdx.x] = s; __syncthreads();
    for (int o = 128; o > 0; o >>= 1) {
        if (threadIdx.x < o) red[threadIdx.x] += red[threadIdx.x + o];
        __syncthreads();
    }
    if (threadIdx.x == 0) pooled[bc] = red[0] * (1.f / (float)HW_);
}

// ---------------- atten = 1 + sigmoid(GN(conv1x1(pooled))) ----------------
__global__ __launch_bounds__(256) void k_atten(const float* __restrict__ pooled,
                                               const float* __restrict__ aw, const float* __restrict__ ab,
                                               const float* __restrict__ g1w, const float* __restrict__ g1b,
                                               float* __restrict__ atten) {
    int b = blockIdx.x;
    __shared__ float pl[C_];
    __shared__ float av[C_];
    int o = threadIdx.x;
    pl[o] = pooled[b * C_ + o];
    __syncthreads();
    float s = ab[o];
    const float* wr = aw + (size_t)o * C_;
    for (int c = 0; c < C_; ++c) s += wr[c] * pl[c];
    av[o] = s; __syncthreads();
    int g = o >> 3;
    float m = 0.f;
    for (int i = 0; i < 8; ++i) m += av[g * 8 + i];
    m *= 0.125f;
    float v = 0.f;
    for (int i = 0; i < 8; ++i) { float d = av[g * 8 + i] - m; v += d * d; }
    v *= 0.125f;
    float xn = (s - m) * rsqrtf(v + 1e-5f);
    float gn = xn * g1w[o] + g1b[o];
    atten[b * C_ + o] = 1.f + 1.f / (1.f + expf(-gn));   // store (1+sigmoid) scale
}

// ---------------- bilinear 2x upsample, channel-first ----------------
__global__ __launch_bounds__(256) void k_up(const float* __restrict__ fs, float* __restrict__ up_cf) {
    int bc = blockIdx.x;
    const float* src = fs + (size_t)bc * (Hs_ * Ws_);
    float* dst = up_cf + (size_t)bc * HW_;
    for (int i = threadIdx.x; i < HW_; i += 256) {
        int y = i / W_, x = i - y * W_;
        float syf = fmaxf((y + 0.5f) * 0.5f - 0.5f, 0.f);
        float sxf = fmaxf((x + 0.5f) * 0.5f - 0.5f, 0.f);
        int y0 = (int)syf, x0 = (int)sxf;
        int y1 = min(y0 + 1, Hs_ - 1), x1 = min(x0 + 1, Ws_ - 1);
        float fy = syf - (float)y0, fx = sxf - (float)x0;
        float v00 = src[y0 * Ws_ + x0], v01 = src[y0 * Ws_ + x1];
        float v10 = src[y1 * Ws_ + x0], v11 = src[y1 * Ws_ + x1];
        dst[i] = v00 * (1.f - fy) * (1.f - fx) + v01 * (1.f - fy) * fx
               + v10 * fy * (1.f - fx) + v11 * fy * fx;
    }
}

// ---------------- [B][C][HW] -> [B][HW][C] ----------------
__global__ __launch_bounds__(256) void k_transpose(const float* __restrict__ src, float* __restrict__ dst) {
    __shared__ float t[32][33];
    int b = blockIdx.z;
    int c0 = blockIdx.x * 32, p0 = blockIdx.y * 32;
    const float* s = src + (size_t)b * C_ * HW_;
    float* d = dst + (size_t)b * HW_ * C_;
    int tx = threadIdx.x & 31, ty = threadIdx.x >> 5;   // 32 x 8
    for (int i = 0; i < 32; i += 8)
        t[ty + i][tx] = s[(size_t)(c0 + ty + i) * HW_ + p0 + tx];
    __syncthreads();
    for (int i = 0; i < 32; i += 8)
        d[(size_t)(p0 + ty + i) * C_ + c0 + tx] = t[tx][ty + i];
}

__global__ void k_gnfin(float* stats, float inv_count) {
    int t = threadIdx.x;  // 64 = B*32
    float s = stats[t * 2], q = stats[t * 2 + 1];
    float mean = s * inv_count;
    float var = q * inv_count - mean * mean;
    stats[t * 2] = mean;
    stats[t * 2 + 1] = rsqrtf(var + 1e-5f);
}

__global__ __launch_bounds__(256) void k_gnapply(float* __restrict__ buf, const float* __restrict__ stats,
                                                 const float* __restrict__ w, const float* __restrict__ bgn) {
    int bc = blockIdx.x; int b = bc / C_; int c = bc - b * C_; int g = c >> 3;
    float mean = stats[(b * GNG_ + g) * 2], rstd = stats[(b * GNG_ + g) * 2 + 1];
    float sw = w[c] * rstd;
    float sb = bgn[c] - mean * sw;
    float* p = buf + (size_t)bc * HW_;
    for (int i = threadIdx.x; i < HW_; i += 256) p[i] = p[i] * sw + sb;
}

// ------- bf16 hi/lo split helpers (RTNE) -------
__device__ __forceinline__ void bf16split(float v, ushort& h, ushort& l) {
    unsigned u = __float_as_uint(v);
    unsigned hr = (u + 0x7FFFu + ((u >> 16) & 1u)) >> 16;
    float hf = __uint_as_float(hr << 16);
    unsigned u2 = __float_as_uint(v - hf);
    unsigned lr_ = (u2 + 0x7FFFu + ((u2 >> 16) & 1u)) >> 16;
    h = (ushort)hr; l = (ushort)lr_;
}

// ------- weight prep: comw[216][256][3][3] -> awt_{h,l}[72][256][32] (tap-major k-steps, m-padded) -------
__global__ __launch_bounds__(256) void k_prepw(const float* __restrict__ w,
                                               ushort* __restrict__ ah, ushort* __restrict__ al) {
    int q = blockIdx.x;        // 72 k-steps: tap = q>>3, cb = q&7
    int m = threadIdx.x;       // 256 rows (pad >=216 with zeros)
    int tap = q >> 3, cb = q & 7;
    ushort hbuf[32], lbuf[32];
    #pragma unroll
    for (int kk = 0; kk < 32; ++kk) {
        float v = 0.f;
        if (m < OMC_) v = w[((size_t)m * 256 + cb * 32 + kk) * 9 + tap];
        bf16split(v, hbuf[kk], lbuf[kk]);
    }
    size_t base = ((size_t)q * 256 + m) * 32;
    #pragma unroll
    for (int i = 0; i < 4; ++i) {
        ((uint4*)(ah + base))[i] = ((const uint4*)hbuf)[i];
        ((uint4*)(al + base))[i] = ((const uint4*)lbuf)[i];
    }
}

// ------- dcn weight prep: dcnw[256][256][3][3] -> dwt_{h,l}[72][256][32], q = g*9+k -------
__global__ __launch_bounds__(256) void k_prepdw(const float* __restrict__ w,
                                                ushort* __restrict__ dh, ushort* __restrict__ dl) {
    int q = blockIdx.x;        // 72: g = q/9, k = q%9
    int m = threadIdx.x;       // 256 output channels
    int g = q / 9, k = q - g * 9;
    ushort hbuf[32], lbuf[32];
    #pragma unroll
    for (int kk = 0; kk < 32; ++kk) {
        float v = w[((size_t)m * 256 + g * 32 + kk) * 9 + k];
        bf16split(v, hbuf[kk], lbuf[kk]);
    }
    size_t base = ((size_t)q * 256 + m) * 32;
    #pragma unroll
    for (int i = 0; i < 4; ++i) {
        ((uint4*)(dh + base))[i] = ((const uint4*)hbuf)[i];
        ((uint4*)(dl + base))[i] = ((const uint4*)lbuf)[i];
    }
}

// ------- 1x1 weight prep: w[256][K] -> {h,l}[K/32][256][32] -------
__global__ __launch_bounds__(256) void k_prepcw(const float* __restrict__ w, int K,
                                                ushort* __restrict__ h, ushort* __restrict__ l) {
    int q = blockIdx.x;        // K/32 chunks
    int m = threadIdx.x;       // 256 rows
    ushort hbuf[32], lbuf[32];
    #pragma unroll
    for (int kk = 0; kk < 32; ++kk) {
        float v = w[(size_t)m * K + q * 32 + kk];
        bf16split(v, hbuf[kk], lbuf[kk]);
    }
    size_t base = ((size_t)q * 256 + m) * 32;
    #pragma unroll
    for (int i = 0; i < 4; ++i) {
        ((uint4*)(h + base))[i] = ((const uint4*)hbuf)[i];
        ((uint4*)(l + base))[i] = ((const uint4*)lbuf)[i];
    }
}

// ------- activation prep (scaled): src[b][256][HW] -> xh/xl [b][8][HW][32] -------
__global__ __launch_bounds__(256) void k_prepxs(const float* __restrict__ src,
                                                ushort* __restrict__ xhh, ushort* __restrict__ xll,
                                                const float* __restrict__ chscale, float cscale) {
    int pt = blockIdx.x;       // 144 tiles of 64 px
    int cb = blockIdx.y;       // 8
    int b  = blockIdx.z;       // 2
    int p0 = pt * 64;
    __shared__ __align__(16) ushort th[32][72];
    __shared__ __align__(16) ushort tl[32][72];
    int t = threadIdx.x;
    int c = t >> 3, j8 = (t & 7) * 8;
    float sc = cscale;
    if (chscale) sc *= chscale[b * 256 + cb * 32 + c];
    const float* srow = src + ((size_t)b * 256 + cb * 32 + c) * HW_ + p0 + j8;
    float4 v0 = *(const float4*)srow;
    float4 v1 = *(const float4*)(srow + 4);
    float vv[8] = {v0.x, v0.y, v0.z, v0.w, v1.x, v1.y, v1.z, v1.w};
    ushort hv[8], lv[8];
    #pragma unroll
    for (int i = 0; i < 8; ++i) bf16split(vv[i] * sc, hv[i], lv[i]);
    *(uint4*)&th[c][j8] = *(const uint4*)hv;
    *(uint4*)&tl[c][j8] = *(const uint4*)lv;
    __syncthreads();
    int p = t >> 2, ch = (t & 3) * 8;
    ushort oh[8], ol[8];
    #pragma unroll
    for (int i = 0; i < 8; ++i) { oh[i] = th[ch + i][p]; ol[i] = tl[ch + i][p]; }
    size_t obase = (((size_t)(b * 8 + cb)) * HW_ + p0 + p) * 32 + ch;
    *(uint4*)(xhh + obase) = *(const uint4*)oh;
    *(uint4*)(xll + obase) = *(const uint4*)ol;
}

// ------- activation prep with fused GroupNorm: offf_raw -> xh/xl [b][8][HW][32] -------
__global__ __launch_bounds__(256) void k_prepxg(const float* __restrict__ src,
                                                const float* __restrict__ stats,
                                                const float* __restrict__ gw, const float* __restrict__ gb,
                                                ushort* __restrict__ xhh, ushort* __restrict__ xll) {
    int pt = blockIdx.x;       // 144 tiles of 64 px
    int cb = blockIdx.y;       // 8
    int b  = blockIdx.z;       // 2
    int p0 = pt * 64;
    __shared__ __align__(16) ushort th[32][72];
    __shared__ __align__(16) ushort tl[32][72];
    int t = threadIdx.x;
    int c = t >> 3, j8 = (t & 7) * 8;
    int chg = cb * 32 + c;
    int g = chg >> 3;
    float mean = stats[(b * GNG_ + g) * 2], rstd = stats[(b * GNG_ + g) * 2 + 1];
    float sw = gw[chg] * rstd;
    float sb = gb[chg] - mean * sw;
    const float* srow = src + ((size_t)b * 256 + chg) * HW_ + p0 + j8;
    float4 v0 = *(const float4*)srow;
    float4 v1 = *(const float4*)(srow + 4);
    float vv[8] = {v0.x, v0.y, v0.z, v0.w, v1.x, v1.y, v1.z, v1.w};
    ushort hv[8], lv[8];
    #pragma unroll
    for (int i = 0; i < 8; ++i) bf16split(vv[i] * sw + sb, hv[i], lv[i]);
    *(uint4*)&th[c][j8] = *(const uint4*)hv;
    *(uint4*)&tl[c][j8] = *(const uint4*)lv;
    __syncthreads();
    int p = t >> 2, ch = (t & 3) * 8;
    ushort oh[8], ol[8];
    #pragma unroll
    for (int i = 0; i < 8; ++i) { oh[i] = th[ch + i][p]; ol[i] = tl[ch + i][p]; }
    size_t obase = (((size_t)(b * 8 + cb)) * HW_ + p0 + p) * 32 + ch;
    *(uint4*)(xhh + obase) = *(const uint4*)oh;
    *(uint4*)(xll + obase) = *(const uint4*)ol;
}

// ------- conv1x1 via MFMA (split-bf16), QC=8 chunks. Optional accumulate-in and GN partial stats. -------
__global__ __launch_bounds__(256) void k_conv1x1m(const ushort* __restrict__ wh, const ushort* __restrict__ wl,
                                                  const ushort* __restrict__ xh, const ushort* __restrict__ xl,
                                                  const float* __restrict__ bias, const float* __restrict__ addin,
                                                  float* __restrict__ out, float* __restrict__ stats) {
    int nb = blockIdx.x;
    int mb = blockIdx.y;
    int b  = blockIdx.z;
    int n0 = nb * 64;
    __shared__ __align__(16) ushort Ah[128 * 32];
    __shared__ __align__(16) ushort Al[128 * 32];
    __shared__ __align__(16) ushort Bh[64 * 32];
    __shared__ __align__(16) ushort Bl[64 * 32];
    __shared__ float gsum[16], gsq[16];
    int tid = threadIdx.x;
    if (tid < 16) { gsum[tid] = 0.f; gsq[tid] = 0.f; }
    int lane = tid & 63, wv = tid >> 6;
    int mh = (wv >> 1) * 64;
    int nq = (wv & 1) * 32;
    int lr = lane & 31;
    int kg = lane >> 5;

    f32x16 acc[2] = {};
    int sn = tid >> 2, sch = tid & 3;

    for (int q = 0; q < 8; ++q) {
        // ---- stage A: weights 128x32 (chunk-swizzled) ----
        const uint4* gah = (const uint4*)(wh + ((size_t)q * 256 + mb * 128) * 32);
        const uint4* gal = (const uint4*)(wl + ((size_t)q * 256 + mb * 128) * 32);
        uint4* sah = (uint4*)Ah; uint4* sal = (uint4*)Al;
        #pragma unroll
        for (int i = 0; i < 2; ++i) {
            int ci = i * 256 + tid;
            int m = ci >> 2, c4 = ci & 3;
            int sw = c4 ^ ((m >> 1) & 3);
            sah[m * 4 + sw] = gah[ci];
            sal[m * 4 + sw] = gal[ci];
        }
        // ---- stage B: activations from [b][8][HW][32] ----
        {
            size_t sidx = (((size_t)(b * 8 + q)) * HW_ + n0 + sn) * 32 + sch * 8;
            uint4 vh = *(const uint4*)(xh + sidx);
            uint4 vl = *(const uint4*)(xl + sidx);
            int sw = sch ^ ((sn >> 1) & 3);
            ((uint4*)Bh)[sn * 4 + sw] = vh;
            ((uint4*)Bl)[sn * 4 + sw] = vl;
        }
        __syncthreads();
        // ---- compute: 2 k-subs of 16 ----
        #pragma unroll
        for (int s = 0; s < 2; ++s) {
            int chnk = 2 * s + kg;
            int nn = nq + lr;
            int bby = nn * 64 + ((chnk ^ ((nn >> 1) & 3)) << 4);
            short8 bh = *(const short8*)((const char*)Bh + bby);
            short8 bl = *(const short8*)((const char*)Bl + bby);
            #pragma unroll
            for (int f = 0; f < 2; ++f) {
                int row = mh + f * 32 + lr;
                int aby = row * 64 + ((chnk ^ ((row >> 1) & 3)) << 4);
                short8 a_h = *(const short8*)((const char*)Ah + aby);
                short8 a_l = *(const short8*)((const char*)Al + aby);
                acc[f] = __builtin_amdgcn_mfma_f32_32x32x16_bf16(a_h, bh, acc[f], 0, 0, 0);
                acc[f] = __builtin_amdgcn_mfma_f32_32x32x16_bf16(a_h, bl, acc[f], 0, 0, 0);
                acc[f] = __builtin_amdgcn_mfma_f32_32x32x16_bf16(a_l, bh, acc[f], 0, 0, 0);
            }
        }
        __syncthreads();
    }
    // ---- epilogue: (bias | addin) + store + optional GN partial stats ----
    int pix = n0 + nq + lr;
    size_t obase = ((size_t)b * 256 + mb * 128) * HW_;
    #pragma unroll
    for (int f = 0; f < 2; ++f) {
        #pragma unroll
        for (int r2 = 0; r2 < 4; ++r2) {
            float qs = 0.f, qq = 0.f;
            #pragma unroll
            for (int r3 = 0; r3 < 4; ++r3) {
                int ml = mh + f * 32 + 8 * r2 + 4 * kg + r3;
                size_t oi = obase + (size_t)ml * HW_ + pix;
                float base = addin ? addin[oi] : bias[mb * 128 + ml];
                float v = acc[f][r2 * 4 + r3] + base;
                out[oi] = v;
                qs += v; qq += v * v;
            }
            if (stats) {
                int gl = (mh >> 3) + f * 4 + r2;
                atomicAdd(&gsum[gl], qs);
                atomicAdd(&gsq[gl], qq);
            }
        }
    }
    __syncthreads();
    if (stats && tid < 16) {
        atomicAdd(&stats[((size_t)b * GNG_ + mb * 16 + tid) * 2 + 0], gsum[tid]);
        atomicAdd(&stats[((size_t)b * GNG_ + mb * 16 + tid) * 2 + 1], gsq[tid]);
    }
}

// ------- conv3x3 via MFMA (split-bf16, implicit im2col). K split in 2 across blockIdx.y -------
__global__ __launch_bounds__(256) void k_conv3x3m(const ushort* __restrict__ awt_h, const ushort* __restrict__ awt_l,
                                                  const ushort* __restrict__ xh, const ushort* __restrict__ xl,
                                                  const float* __restrict__ bias,
                                                  float* __restrict__ om1, float* __restrict__ om2) {
    int nb = blockIdx.x;        // 144 pixel tiles of 64
    int ks = blockIdx.y;        // K-split half
    int b  = blockIdx.z;
    int n0 = nb * 64;
    __shared__ __align__(16) ushort Ah[256 * 32];
    __shared__ __align__(16) ushort Al[256 * 32];
    __shared__ __align__(16) ushort Bh[64 * 32];
    __shared__ __align__(16) ushort Bl[64 * 32];
    int tid = threadIdx.x;
    int lane = tid & 63, wv = tid >> 6;
    int mh = (wv >> 1) * 128;
    int nq = (wv & 1) * 32;
    int lr = lane & 31;
    int kg = lane >> 5;

    f32x16 acc[4] = {};

    int sn = tid >> 2, sch = tid & 3;
    int sp = n0 + sn;
    int spy = sp / W_, spx = sp - spy * W_;

    for (int q = ks * 36; q < ks * 36 + 36; ++q) {
        int tap = q >> 3, cb = q & 7;
        int dy = tap / 3 - 1, dx = tap % 3 - 1;
        const uint4* gah = (const uint4*)(awt_h + (size_t)q * 8192);
        const uint4* gal = (const uint4*)(awt_l + (size_t)q * 8192);
        uint4* sah = (uint4*)Ah; uint4* sal = (uint4*)Al;
        #pragma unroll
        for (int i = 0; i < 4; ++i) {
            int ci = i * 256 + tid;
            int m = ci >> 2, c4 = ci & 3;
            int sw = c4 ^ ((m >> 1) & 3);
            sah[m * 4 + sw] = gah[ci];
            sal[m * 4 + sw] = gal[ci];
        }
        {
            int y = spy + dy, x = spx + dx;
            uint4 vh = {0u, 0u, 0u, 0u}, vl = {0u, 0u, 0u, 0u};
            if ((unsigned)y < (unsigned)H_ && (unsigned)x < (unsigned)W_) {
                size_t sidx = (((size_t)(b * 8 + cb)) * HW_ + y * W_ + x) * 32 + sch * 8;
                vh = *(const uint4*)(xh + sidx);
                vl = *(const uint4*)(xl + sidx);
            }
            int sw = sch ^ ((sn >> 1) & 3);
            ((uint4*)Bh)[sn * 4 + sw] = vh;
            ((uint4*)Bl)[sn * 4 + sw] = vl;
        }
        __syncthreads();
        #pragma unroll
        for (int s = 0; s < 2; ++s) {
            int chnk = 2 * s + kg;
            int nn = nq + lr;
            int bby = nn * 64 + ((chnk ^ ((nn >> 1) & 3)) << 4);
            short8 bh = *(const short8*)((const char*)Bh + bby);
            short8 bl = *(const short8*)((const char*)Bl + bby);
            #pragma unroll
            for (int f = 0; f < 4; ++f) {
                int row = mh + f * 32 + lr;
                int aby = row * 64 + ((chnk ^ ((row >> 1) & 3)) << 4);
                short8 a_h = *(const short8*)((const char*)Ah + aby);
                short8 a_l = *(const short8*)((const char*)Al + aby);
                acc[f] = __builtin_amdgcn_mfma_f32_32x32x16_bf16(a_h, bh, acc[f], 0, 0, 0);
                acc[f] = __builtin_amdgcn_mfma_f32_32x32x16_bf16(a_h, bl, acc[f], 0, 0, 0);
                acc[f] = __builtin_amdgcn_mfma_f32_32x32x16_bf16(a_l, bh, acc[f], 0, 0, 0);
            }
        }
        __syncthreads();
    }
    float* outp = (ks ? om2 : om1) + (size_t)b * OMC_ * HW_;
    int pix = n0 + nq + lr;
    #pragma unroll
    for (int f = 0; f < 4; ++f) {
        #pragma unroll
        for (int r = 0; r < 16; ++r) {
            int m = mh + f * 32 + (r & 3) + 8 * (r >> 2) + 4 * kg;
            if (m < OMC_) {
                float v = acc[f][r] + (ks ? 0.f : bias[m]);
                outp[(size_t)m * HW_ + pix] = v;
            }
        }
    }
}

// ------- modulated deformable conv via MFMA (split-bf16) + bias + relu + add feat_arm -------
__global__ __launch_bounds__(256) void k_dcnm(const float* __restrict__ up_cl,
                                              const float* __restrict__ om1, const float* __restrict__ om2,
                                              const ushort* __restrict__ dwh, const ushort* __restrict__ dwl,
                                              const float* __restrict__ dcnb, const float* __restrict__ arm,
                                              float* __restrict__ outp) {
    int nb = blockIdx.x;        // 144 pixel tiles of 64
    int mb = blockIdx.y;        // 2 M-halves of 128
    int b  = blockIdx.z;
    int n0 = nb * 64;
    __shared__ __align__(16) ushort Ah[128 * 32];
    __shared__ __align__(16) ushort Al[128 * 32];
    __shared__ __align__(16) ushort Bh[64 * 32];
    __shared__ __align__(16) ushort Bl[64 * 32];
    __shared__ float w4s[64][4];
    __shared__ int   yxs[64];
    int tid = threadIdx.x;
    int lane = tid & 63, wv = tid >> 6;
    int mh = (wv >> 1) * 64;
    int nq = (wv & 1) * 32;
    int lr = lane & 31;
    int kg = lane >> 5;

    f32x16 acc[2] = {};

    int sn = tid >> 2, sch = tid & 3;
    const float* upb = up_cl + (size_t)b * HW_ * 256;

    for (int q = 0; q < 72; ++q) {
        int g = q / 9, k = q - g * 9;
        const uint4* gah = (const uint4*)(dwh + ((size_t)q * 256 + mb * 128) * 32);
        const uint4* gal = (const uint4*)(dwl + ((size_t)q * 256 + mb * 128) * 32);
        uint4* sah = (uint4*)Ah; uint4* sal = (uint4*)Al;
        #pragma unroll
        for (int i = 0; i < 2; ++i) {
            int ci = i * 256 + tid;
            int m = ci >> 2, c4 = ci & 3;
            int sw = c4 ^ ((m >> 1) & 3);
            sah[m * 4 + sw] = gah[ci];
            sal[m * 4 + sw] = gal[ci];
        }
        if (tid < 64) {
            int pix = n0 + tid;
            int hh = pix / W_, ww = pix - hh * W_;
            size_t i_oy = ((size_t)b * OMC_ + g * 18 + 2 * k) * HW_ + pix;
            size_t i_mv = ((size_t)b * OMC_ + 144 + g * 9 + k) * HW_ + pix;
            float oy = om1[i_oy] + om2[i_oy];
            float ox = om1[i_oy + HW_] + om2[i_oy + HW_];
            float mv = om1[i_mv] + om2[i_mv];
            float m = 1.f / (1.f + expf(-mv));
            float pyf = oy + (float)(hh - 1 + k / 3);
            float pxf = ox + (float)(ww - 1 + k % 3);
            float y0f = floorf(pyf), x0f = floorf(pxf);
            int y0 = (int)y0f, x0 = (int)x0f;
            float fy = pyf - y0f, fx = pxf - x0f;
            float wy0 = (y0 >= 0 && y0 < H_) ? (1.f - fy) : 0.f;
            float wy1 = (y0 + 1 >= 0 && y0 + 1 < H_) ? fy : 0.f;
            float wx0 = (x0 >= 0 && x0 < W_) ? (1.f - fx) : 0.f;
            float wx1 = (x0 + 1 >= 0 && x0 + 1 < W_) ? fx : 0.f;
            w4s[tid][0] = wy0 * wx0 * m; w4s[tid][1] = wy0 * wx1 * m;
            w4s[tid][2] = wy1 * wx0 * m; w4s[tid][3] = wy1 * wx1 * m;
            yxs[tid] = (y0 << 16) | (x0 & 0xFFFF);
        }
        __syncthreads();
        {
            float4 wv4 = *(const float4*)w4s[sn];
            int yx = yxs[sn];
            int y0 = yx >> 16;
            int x0 = (int)(short)(yx & 0xFFFF);
            int y0c = min(max(y0, 0), H_ - 1), y1c = min(max(y0 + 1, 0), H_ - 1);
            int x0c = min(max(x0, 0), W_ - 1), x1c = min(max(x0 + 1, 0), W_ - 1);
            size_t chof = (size_t)g * 32 + sch * 8;
            const float* p00 = upb + (size_t)(y0c * W_ + x0c) * 256 + chof;
            const float* p01 = upb + (size_t)(y0c * W_ + x1c) * 256 + chof;
            const float* p10 = upb + (size_t)(y1c * W_ + x0c) * 256 + chof;
            const float* p11 = upb + (size_t)(y1c * W_ + x1c) * 256 + chof;
            ushort hv[8], lv[8];
            #pragma unroll
            for (int h2 = 0; h2 < 2; ++h2) {
                float4 t00 = *(const float4*)(p00 + h2 * 4);
                float4 t01 = *(const float4*)(p01 + h2 * 4);
                float4 t10 = *(const float4*)(p10 + h2 * 4);
                float4 t11 = *(const float4*)(p11 + h2 * 4);
                float v0 = wv4.x * t00.x + wv4.y * t01.x + wv4.z * t10.x + wv4.w * t11.x;
                float v1 = wv4.x * t00.y + wv4.y * t01.y + wv4.z * t10.y + wv4.w * t11.y;
                float v2 = wv4.x * t00.z + wv4.y * t01.z + wv4.z * t10.z + wv4.w * t11.z;
                float v3 = wv4.x * t00.w + wv4.y * t01.w + wv4.z * t10.w + wv4.w * t11.w;
                bf16split(v0, hv[h2 * 4 + 0], lv[h2 * 4 + 0]);
                bf16split(v1, hv[h2 * 4 + 1], lv[h2 * 4 + 1]);
                bf16split(v2, hv[h2 * 4 + 2], lv[h2 * 4 + 2]);
                bf16split(v3, hv[h2 * 4 + 3], lv[h2 * 4 + 3]);
            }
            int sw = sch ^ ((sn >> 1) & 3);
            ((uint4*)Bh)[sn * 4 + sw] = *(const uint4*)hv;
            ((uint4*)Bl)[sn * 4 + sw] = *(const uint4*)lv;
        }
        __syncthreads();
        #pragma unroll
        for (int s = 0; s < 2; ++s) {
            int chnk = 2 * s + kg;
            int nn = nq + lr;
            int bby = nn * 64 + ((chnk ^ ((nn >> 1) & 3)) << 4);
            short8 bh = *(const short8*)((const char*)Bh + bby);
            short8 bl = *(const short8*)((const char*)Bl + bby);
            #pragma unroll
            for (int f = 0; f < 2; ++f) {
                int row = mh + f * 32 + lr;
                int aby = row * 64 + ((chnk ^ ((row >> 1) & 3)) << 4);
                short8 a_h = *(const short8*)((const char*)Ah + aby);
                short8 a_l = *(const short8*)((const char*)Al + aby);
                acc[f] = __builtin_amdgcn_mfma_f32_32x32x16_bf16(a_h, bh, acc[f], 0, 0, 0);
                acc[f] = __builtin_amdgcn_mfma_f32_32x32x16_bf16(a_h, bl, acc[f], 0, 0, 0);
                acc[f] = __builtin_amdgcn_mfma_f32_32x32x16_bf16(a_l, bh, acc[f], 0, 0, 0);
            }
        }
        __syncthreads();
    }
    int pix = n0 + nq + lr;
    #pragma unroll
    for (int f = 0; f < 2; ++f) {
        #pragma unroll
        for (int r = 0; r < 16; ++r) {
            int m = mb * 128 + mh + f * 32 + (r & 3) + 8 * (r >> 2) + 4 * kg;
            float v = acc[f][r] + dcnb[m];
            v = fmaxf(v, 0.f) + arm[((size_t)b * 256 + m) * HW_ + pix];
            outp[((size_t)b * 256 + m) * HW_ + pix] = v;
        }
    }
}

extern "C" void kernel_launch(void* const* d_in, const int* in_sizes, int n_in,
                              void* d_out, int out_size, void* d_ws, size_t ws_size,
                              hipStream_t stream) {
    const float* feat_l = (const float*)d_in[0];
    const float* feat_s = (const float*)d_in[1];
    const float* aw  = (const float*)d_in[2];
    const float* ab  = (const float*)d_in[3];
    const float* g1w = (const float*)d_in[4];
    const float* g1b = (const float*)d_in[5];
    const float* cw  = (const float*)d_in[6];
    const float* cb  = (const float*)d_in[7];
    const float* g2w = (const float*)d_in[8];
    const float* g2b = (const float*)d_in[9];
    const float* ow  = (const float*)d_in[10];
    const float* ob  = (const float*)d_in[11];
    const float* gow = (const float*)d_in[12];
    const float* gob = (const float*)d_in[13];
    const float* comw= (const float*)d_in[14];
    const float* comb= (const float*)d_in[15];
    const float* dcnw= (const float*)d_in[16];
    const float* dcnb= (const float*)d_in[17];
    float* out = (float*)d_out;
    float* ws = (float*)d_ws;

    // Workspace (~96.7 MB, within the proven ~97 MB envelope), stream-order-safe aliasing:
    //   xreg (single [b][8][HW][32] h+l staging): conv#1 X -> conv#2a X (arm) -> conv#2b X (up*2) -> conv3x3 X
    //   wtreg: c1,c2 (1x1 weights) -> awth/awtl (conv3x3) -> dwh/dwl (dcn)
    //   offf : conv#2 raw out (accumulated over two passes); dead after prepxg -> om1
    //   up_cf: dead after prepxs(up)                                          -> om2
    size_t off = 0;
    float* up_cf = ws + off; off += (size_t)B_ * C_ * HW_;
    float* up_cl = ws + off; off += (size_t)B_ * C_ * HW_;
    float* arm   = ws + off; off += (size_t)B_ * C_ * HW_;
    float* offf  = ws + off; off += (size_t)B_ * C_ * HW_;
    float* wtreg = ws + off; off += (size_t)2304 * 256;           // 589824 floats (1,179,648 ushorts)
    float* xreg  = ws + off; off += (size_t)B_ * 8 * HW_ * 32;    // 4,718,592 floats = 9,437,184 ushorts (h+l)
    float* pooled= ws + off; off += B_ * C_;
    float* atten = ws + off; off += B_ * C_;
    float* stats = ws + off; off += 4 * B_ * GNG_;
    float* stats_arm = stats;
    float* stats_off = stats + 2 * B_ * GNG_;

    // wtreg overlays (sequential lifetimes)
    ushort* c1h = (ushort*)wtreg;                         // 8*256*32 us
    ushort* c1l = c1h + (size_t)8 * 256 * 32;
    ushort* c2h = c1l + (size_t)8 * 256 * 32;             // 16*256*32 us
    ushort* c2l = c2h + (size_t)16 * 256 * 32;            // total 393216 us <= 1179648 capacity
    ushort* awth = (ushort*)wtreg;                        // after conv1x1m#2b
    ushort* awtl = awth + (size_t)72 * 256 * 32;
    ushort* dwh  = (ushort*)wtreg;                        // after conv3x3m
    ushort* dwl  = dwh + (size_t)72 * 256 * 32;

    // xreg overlays (sequential lifetimes)
    ushort* xh = (ushort*)xreg;
    ushort* xl = xh + (size_t)B_ * 8 * HW_ * 32;

    float* om1 = offf;    // alias: offf dead after k_prepxg
    float* om2 = up_cf;   // alias: up_cf dead after prepxs(up)

    hipMemsetAsync(stats, 0, 4 * B_ * GNG_ * sizeof(float), stream);
    k_pool<<<B_ * C_, 256, 0, stream>>>(feat_l, pooled);
    k_atten<<<B_, 256, 0, stream>>>(pooled, aw, ab, g1w, g1b, atten);
    k_up<<<B_ * C_, 256, 0, stream>>>(feat_s, up_cf);
    k_transpose<<<dim3(8, 288, B_), 256, 0, stream>>>(up_cf, up_cl);

    // conv#1: arm_raw = cw @ (feat_l * atten) + cb, GN stats
    k_prepcw<<<8, 256, 0, stream>>>(cw, 256, c1h, c1l);
    k_prepxs<<<dim3(144, 8, B_), 256, 0, stream>>>(feat_l, xh, xl, atten, 1.f);
    k_conv1x1m<<<dim3(144, 2, B_), 256, 0, stream>>>(c1h, c1l, xh, xl, cb, nullptr, arm, stats_arm);
    k_gnfin<<<1, 64, 0, stream>>>(stats_arm, 1.f / (8.f * HW_));
    k_gnapply<<<B_ * C_, 256, 0, stream>>>(arm, stats_arm, g2w, g2b);

    // conv#2 in two K-halves sharing one X buffer:
    //   #2a: offf = ow[:, :256] @ arm_gn + ob            (no stats)
    //   #2b: offf += ow[:, 256:] @ (up*2), GN stats on final values
    k_prepcw<<<16, 256, 0, stream>>>(ow, 512, c2h, c2l);
    k_prepxs<<<dim3(144, 8, B_), 256, 0, stream>>>(arm, xh, xl, nullptr, 1.f);
    k_conv1x1m<<<dim3(144, 2, B_), 256, 0, stream>>>(c2h, c2l, xh, xl, ob, nullptr, offf, nullptr);
    k_prepxs<<<dim3(144, 8, B_), 256, 0, stream>>>(up_cf, xh, xl, nullptr, 2.f);
    k_conv1x1m<<<dim3(144, 2, B_), 256, 0, stream>>>(c2h + (size_t)8 * 256 * 32, c2l + (size_t)8 * 256 * 32,
                                                     xh, xl, ob, offf, offf, stats_off);
    k_gnfin<<<1, 64, 0, stream>>>(stats_off, 1.f / (8.f * HW_));

    // conv3x3 (GN fused into X-prep)
    k_prepw<<<72, 256, 0, stream>>>(comw, awth, awtl);
    k_prepxg<<<dim3(144, 8, B_), 256, 0, stream>>>(offf, stats_off, gow, gob, xh, xl);
    k_conv3x3m<<<dim3(144, 2, B_), 256, 0, stream>>>(awth, awtl, xh, xl, comb, om1, om2);

    // deformable conv + epilogue
    k_prepdw<<<72, 256, 0, stream>>>(dcnw, dwh, dwl);
    k_dcnm<<<dim3(144, 2, B_), 256, 0, stream>>>(up_cl, om1, om2, dwh, dwl, dcnb, arm, out);
}

// Round 11
// 544.132 us; speedup vs baseline: 3.0762x; 1.0310x over previous
//
#include <hip/hip_runtime.h>

constexpr int B_ = 2, C_ = 256, H_ = 96, W_ = 96, HW_ = H_ * W_;
constexpr int Hs_ = 48, Ws_ = 48;
constexpr int OMC_ = 216;          // DG*3*KK
constexpr int GNG_ = 32;           // groupnorm groups for C=256 -> 8 ch/group

typedef __attribute__((ext_vector_type(8))) short short8;
typedef __attribute__((ext_vector_type(16))) float f32x16;

// ---------------- global average pool over HW per (b,c) ----------------
__global__ __launch_bounds__(256) void k_pool(const float* __restrict__ x, float* __restrict__ pooled) {
    int bc = blockIdx.x;
    const float* p = x + (size_t)bc * HW_;
    float s = 0.f;
    for (int i = threadIdx.x; i < HW_; i += 256) s += p[i];
    __shared__ float red[256];
    red[threadIdx.x] = s; __syncthreads();
    for (int o = 128; o > 0; o >>= 1) {
        if (threadIdx.x < o) red[threadIdx.x] += red[threadIdx.x + o];
        __syncthreads();
    }
    if (threadIdx.x == 0) pooled[bc] = red[0] * (1.f / (float)HW_);
}

// ---------------- atten = 1 + sigmoid(GN(conv1x1(pooled))) ----------------
__global__ __launch_bounds__(256) void k_atten(const float* __restrict__ pooled,
                                               const float* __restrict__ aw, const float* __restrict__ ab,
                                               const float* __restrict__ g1w, const float* __restrict__ g1b,
                                               float* __restrict__ atten) {
    int b = blockIdx.x;
    __shared__ float pl[C_];
    __shared__ float av[C_];
    int o = threadIdx.x;
    pl[o] = pooled[b * C_ + o];
    __syncthreads();
    float s = ab[o];
    const float* wr = aw + (size_t)o * C_;
    for (int c = 0; c < C_; ++c) s += wr[c] * pl[c];
    av[o] = s; __syncthreads();
    int g = o >> 3;
    float m = 0.f;
    for (int i = 0; i < 8; ++i) m += av[g * 8 + i];
    m *= 0.125f;
    float v = 0.f;
    for (int i = 0; i < 8; ++i) { float d = av[g * 8 + i] - m; v += d * d; }
    v *= 0.125f;
    float xn = (s - m) * rsqrtf(v + 1e-5f);
    float gn = xn * g1w[o] + g1b[o];
    atten[b * C_ + o] = 1.f + 1.f / (1.f + expf(-gn));   // store (1+sigmoid) scale
}

// ---------------- bilinear 2x upsample, channel-first ----------------
__global__ __launch_bounds__(256) void k_up(const float* __restrict__ fs, float* __restrict__ up_cf) {
    int bc = blockIdx.x;
    const float* src = fs + (size_t)bc * (Hs_ * Ws_);
    float* dst = up_cf + (size_t)bc * HW_;
    for (int i = threadIdx.x; i < HW_; i += 256) {
        int y = i / W_, x = i - y * W_;
        float syf = fmaxf((y + 0.5f) * 0.5f - 0.5f, 0.f);
        float sxf = fmaxf((x + 0.5f) * 0.5f - 0.5f, 0.f);
        int y0 = (int)syf, x0 = (int)sxf;
        int y1 = min(y0 + 1, Hs_ - 1), x1 = min(x0 + 1, Ws_ - 1);
        float fy = syf - (float)y0, fx = sxf - (float)x0;
        float v00 = src[y0 * Ws_ + x0], v01 = src[y0 * Ws_ + x1];
        float v10 = src[y1 * Ws_ + x0], v11 = src[y1 * Ws_ + x1];
        dst[i] = v00 * (1.f - fy) * (1.f - fx) + v01 * (1.f - fy) * fx
               + v10 * fy * (1.f - fx) + v11 * fy * fx;
    }
}

// ---------------- [B][C][HW] -> [B][HW][C] ----------------
__global__ __launch_bounds__(256) void k_transpose(const float* __restrict__ src, float* __restrict__ dst) {
    __shared__ float t[32][33];
    int b = blockIdx.z;
    int c0 = blockIdx.x * 32, p0 = blockIdx.y * 32;
    const float* s = src + (size_t)b * C_ * HW_;
    float* d = dst + (size_t)b * HW_ * C_;
    int tx = threadIdx.x & 31, ty = threadIdx.x >> 5;   // 32 x 8
    for (int i = 0; i < 32; i += 8)
        t[ty + i][tx] = s[(size_t)(c0 + ty + i) * HW_ + p0 + tx];
    __syncthreads();
    for (int i = 0; i < 32; i += 8)
        d[(size_t)(p0 + ty + i) * C_ + c0 + tx] = t[tx][ty + i];
}

__global__ void k_gnfin(float* stats, float inv_count) {
    int t = threadIdx.x;  // 64 = B*32
    float s = stats[t * 2], q = stats[t * 2 + 1];
    float mean = s * inv_count;
    float var = q * inv_count - mean * mean;
    stats[t * 2] = mean;
    stats[t * 2 + 1] = rsqrtf(var + 1e-5f);
}

__global__ __launch_bounds__(256) void k_gnapply(float* __restrict__ buf, const float* __restrict__ stats,
                                                 const float* __restrict__ w, const float* __restrict__ bgn) {
    int bc = blockIdx.x; int b = bc / C_; int c = bc - b * C_; int g = c >> 3;
    float mean = stats[(b * GNG_ + g) * 2], rstd = stats[(b * GNG_ + g) * 2 + 1];
    float sw = w[c] * rstd;
    float sb = bgn[c] - mean * sw;
    float* p = buf + (size_t)bc * HW_;
    for (int i = threadIdx.x; i < HW_; i += 256) p[i] = p[i] * sw + sb;
}

// ------- bf16 hi/lo split helpers (RTNE) -------
__device__ __forceinline__ void bf16split(float v, ushort& h, ushort& l) {
    unsigned u = __float_as_uint(v);
    unsigned hr = (u + 0x7FFFu + ((u >> 16) & 1u)) >> 16;
    float hf = __uint_as_float(hr << 16);
    unsigned u2 = __float_as_uint(v - hf);
    unsigned lr_ = (u2 + 0x7FFFu + ((u2 >> 16) & 1u)) >> 16;
    h = (ushort)hr; l = (ushort)lr_;
}

// ------- weight prep: comw[216][256][3][3] -> awt_{h,l}[72][256][32] (tap-major k-steps, m-padded) -------
__global__ __launch_bounds__(256) void k_prepw(const float* __restrict__ w,
                                               ushort* __restrict__ ah, ushort* __restrict__ al) {
    int q = blockIdx.x;        // 72 k-steps: tap = q>>3, cb = q&7
    int m = threadIdx.x;       // 256 rows (pad >=216 with zeros)
    int tap = q >> 3, cb = q & 7;
    ushort hbuf[32], lbuf[32];
    #pragma unroll
    for (int kk = 0; kk < 32; ++kk) {
        float v = 0.f;
        if (m < OMC_) v = w[((size_t)m * 256 + cb * 32 + kk) * 9 + tap];
        bf16split(v, hbuf[kk], lbuf[kk]);
    }
    size_t base = ((size_t)q * 256 + m) * 32;
    #pragma unroll
    for (int i = 0; i < 4; ++i) {
        ((uint4*)(ah + base))[i] = ((const uint4*)hbuf)[i];
        ((uint4*)(al + base))[i] = ((const uint4*)lbuf)[i];
    }
}

// ------- dcn weight prep: dcnw[256][256][3][3] -> dwt_{h,l}[72][256][32], q = g*9+k -------
__global__ __launch_bounds__(256) void k_prepdw(const float* __restrict__ w,
                                                ushort* __restrict__ dh, ushort* __restrict__ dl) {
    int q = blockIdx.x;        // 72: g = q/9, k = q%9
    int m = threadIdx.x;       // 256 output channels
    int g = q / 9, k = q - g * 9;
    ushort hbuf[32], lbuf[32];
    #pragma unroll
    for (int kk = 0; kk < 32; ++kk) {
        float v = w[((size_t)m * 256 + g * 32 + kk) * 9 + k];
        bf16split(v, hbuf[kk], lbuf[kk]);
    }
    size_t base = ((size_t)q * 256 + m) * 32;
    #pragma unroll
    for (int i = 0; i < 4; ++i) {
        ((uint4*)(dh + base))[i] = ((const uint4*)hbuf)[i];
        ((uint4*)(dl + base))[i] = ((const uint4*)lbuf)[i];
    }
}

// ------- 1x1 weight prep: w[256][K] -> {h,l}[K/32][256][32] -------
__global__ __launch_bounds__(256) void k_prepcw(const float* __restrict__ w, int K,
                                                ushort* __restrict__ h, ushort* __restrict__ l) {
    int q = blockIdx.x;        // K/32 chunks
    int m = threadIdx.x;       // 256 rows
    ushort hbuf[32], lbuf[32];
    #pragma unroll
    for (int kk = 0; kk < 32; ++kk) {
        float v = w[(size_t)m * K + q * 32 + kk];
        bf16split(v, hbuf[kk], lbuf[kk]);
    }
    size_t base = ((size_t)q * 256 + m) * 32;
    #pragma unroll
    for (int i = 0; i < 4; ++i) {
        ((uint4*)(h + base))[i] = ((const uint4*)hbuf)[i];
        ((uint4*)(l + base))[i] = ((const uint4*)lbuf)[i];
    }
}

// ------- activation prep (scaled): src[b][256][HW] -> xh/xl [b][8][HW][32] -------
__global__ __launch_bounds__(256) void k_prepxs(const float* __restrict__ src,
                                                ushort* __restrict__ xhh, ushort* __restrict__ xll,
                                                const float* __restrict__ chscale, float cscale) {
    int pt = blockIdx.x;       // 144 tiles of 64 px
    int cb = blockIdx.y;       // 8
    int b  = blockIdx.z;       // 2
    int p0 = pt * 64;
    __shared__ __align__(16) ushort th[32][72];
    __shared__ __align__(16) ushort tl[32][72];
    int t = threadIdx.x;
    int c = t >> 3, j8 = (t & 7) * 8;
    float sc = cscale;
    if (chscale) sc *= chscale[b * 256 + cb * 32 + c];
    const float* srow = src + ((size_t)b * 256 + cb * 32 + c) * HW_ + p0 + j8;
    float4 v0 = *(const float4*)srow;
    float4 v1 = *(const float4*)(srow + 4);
    float vv[8] = {v0.x, v0.y, v0.z, v0.w, v1.x, v1.y, v1.z, v1.w};
    ushort hv[8], lv[8];
    #pragma unroll
    for (int i = 0; i < 8; ++i) bf16split(vv[i] * sc, hv[i], lv[i]);
    *(uint4*)&th[c][j8] = *(const uint4*)hv;
    *(uint4*)&tl[c][j8] = *(const uint4*)lv;
    __syncthreads();
    int p = t >> 2, ch = (t & 3) * 8;
    ushort oh[8], ol[8];
    #pragma unroll
    for (int i = 0; i < 8; ++i) { oh[i] = th[ch + i][p]; ol[i] = tl[ch + i][p]; }
    size_t obase = (((size_t)(b * 8 + cb)) * HW_ + p0 + p) * 32 + ch;
    *(uint4*)(xhh + obase) = *(const uint4*)oh;
    *(uint4*)(xll + obase) = *(const uint4*)ol;
}

// ------- activation prep with fused GroupNorm: offf_raw -> xh/xl [b][8][HW][32] -------
__global__ __launch_bounds__(256) void k_prepxg(const float* __restrict__ src,
                                                const float* __restrict__ stats,
                                                const float* __restrict__ gw, const float* __restrict__ gb,
                                                ushort* __restrict__ xhh, ushort* __restrict__ xll) {
    int pt = blockIdx.x;       // 144 tiles of 64 px
    int cb = blockIdx.y;       // 8
    int b  = blockIdx.z;       // 2
    int p0 = pt * 64;
    __shared__ __align__(16) ushort th[32][72];
    __shared__ __align__(16) ushort tl[32][72];
    int t = threadIdx.x;
    int c = t >> 3, j8 = (t & 7) * 8;
    int chg = cb * 32 + c;
    int g = chg >> 3;
    float mean = stats[(b * GNG_ + g) * 2], rstd = stats[(b * GNG_ + g) * 2 + 1];
    float sw = gw[chg] * rstd;
    float sb = gb[chg] - mean * sw;
    const float* srow = src + ((size_t)b * 256 + chg) * HW_ + p0 + j8;
    float4 v0 = *(const float4*)srow;
    float4 v1 = *(const float4*)(srow + 4);
    float vv[8] = {v0.x, v0.y, v0.z, v0.w, v1.x, v1.y, v1.z, v1.w};
    ushort hv[8], lv[8];
    #pragma unroll
    for (int i = 0; i < 8; ++i) bf16split(vv[i] * sw + sb, hv[i], lv[i]);
    *(uint4*)&th[c][j8] = *(const uint4*)hv;
    *(uint4*)&tl[c][j8] = *(const uint4*)lv;
    __syncthreads();
    int p = t >> 2, ch = (t & 3) * 8;
    ushort oh[8], ol[8];
    #pragma unroll
    for (int i = 0; i < 8; ++i) { oh[i] = th[ch + i][p]; ol[i] = tl[ch + i][p]; }
    size_t obase = (((size_t)(b * 8 + cb)) * HW_ + p0 + p) * 32 + ch;
    *(uint4*)(xhh + obase) = *(const uint4*)oh;
    *(uint4*)(xll + obase) = *(const uint4*)ol;
}

// ------- conv1x1 via MFMA (split-bf16), QC=8 chunks. Optional accumulate-in and GN partial stats. -------
__global__ __launch_bounds__(256) void k_conv1x1m(const ushort* __restrict__ wh, const ushort* __restrict__ wl,
                                                  const ushort* __restrict__ xh, const ushort* __restrict__ xl,
                                                  const float* __restrict__ bias, const float* __restrict__ addin,
                                                  float* __restrict__ out, float* __restrict__ stats) {
    int nb = blockIdx.x;
    int mb = blockIdx.y;
    int b  = blockIdx.z;
    int n0 = nb * 64;
    __shared__ __align__(16) ushort Ah[128 * 32];
    __shared__ __align__(16) ushort Al[128 * 32];
    __shared__ __align__(16) ushort Bh[64 * 32];
    __shared__ __align__(16) ushort Bl[64 * 32];
    __shared__ float gsum[16], gsq[16];
    int tid = threadIdx.x;
    if (tid < 16) { gsum[tid] = 0.f; gsq[tid] = 0.f; }
    int lane = tid & 63, wv = tid >> 6;
    int mh = (wv >> 1) * 64;
    int nq = (wv & 1) * 32;
    int lr = lane & 31;
    int kg = lane >> 5;

    f32x16 acc[2] = {};
    int sn = tid >> 2, sch = tid & 3;

    for (int q = 0; q < 8; ++q) {
        // ---- stage A: weights 128x32 (chunk-swizzled) ----
        const uint4* gah = (const uint4*)(wh + ((size_t)q * 256 + mb * 128) * 32);
        const uint4* gal = (const uint4*)(wl + ((size_t)q * 256 + mb * 128) * 32);
        uint4* sah = (uint4*)Ah; uint4* sal = (uint4*)Al;
        #pragma unroll
        for (int i = 0; i < 2; ++i) {
            int ci = i * 256 + tid;
            int m = ci >> 2, c4 = ci & 3;
            int sw = c4 ^ ((m >> 1) & 3);
            sah[m * 4 + sw] = gah[ci];
            sal[m * 4 + sw] = gal[ci];
        }
        // ---- stage B: activations from [b][8][HW][32] ----
        {
            size_t sidx = (((size_t)(b * 8 + q)) * HW_ + n0 + sn) * 32 + sch * 8;
            uint4 vh = *(const uint4*)(xh + sidx);
            uint4 vl = *(const uint4*)(xl + sidx);
            int sw = sch ^ ((sn >> 1) & 3);
            ((uint4*)Bh)[sn * 4 + sw] = vh;
            ((uint4*)Bl)[sn * 4 + sw] = vl;
        }
        __syncthreads();
        // ---- compute: 2 k-subs of 16 ----
        #pragma unroll
        for (int s = 0; s < 2; ++s) {
            int chnk = 2 * s + kg;
            int nn = nq + lr;
            int bby = nn * 64 + ((chnk ^ ((nn >> 1) & 3)) << 4);
            short8 bh = *(const short8*)((const char*)Bh + bby);
            short8 bl = *(const short8*)((const char*)Bl + bby);
            #pragma unroll
            for (int f = 0; f < 2; ++f) {
                int row = mh + f * 32 + lr;
                int aby = row * 64 + ((chnk ^ ((row >> 1) & 3)) << 4);
                short8 a_h = *(const short8*)((const char*)Ah + aby);
                short8 a_l = *(const short8*)((const char*)Al + aby);
                acc[f] = __builtin_amdgcn_mfma_f32_32x32x16_bf16(a_h, bh, acc[f], 0, 0, 0);
                acc[f] = __builtin_amdgcn_mfma_f32_32x32x16_bf16(a_h, bl, acc[f], 0, 0, 0);
                acc[f] = __builtin_amdgcn_mfma_f32_32x32x16_bf16(a_l, bh, acc[f], 0, 0, 0);
            }
        }
        __syncthreads();
    }
    // ---- epilogue: (bias | addin) + store + optional GN partial stats ----
    int pix = n0 + nq + lr;
    size_t obase = ((size_t)b * 256 + mb * 128) * HW_;
    #pragma unroll
    for (int f = 0; f < 2; ++f) {
        #pragma unroll
        for (int r2 = 0; r2 < 4; ++r2) {
            float qs = 0.f, qq = 0.f;
            #pragma unroll
            for (int r3 = 0; r3 < 4; ++r3) {
                int ml = mh + f * 32 + 8 * r2 + 4 * kg + r3;
                size_t oi = obase + (size_t)ml * HW_ + pix;
                float base = addin ? addin[oi] : bias[mb * 128 + ml];
                float v = acc[f][r2 * 4 + r3] + base;
                out[oi] = v;
                qs += v; qq += v * v;
            }
            if (stats) {
                int gl = (mh >> 3) + f * 4 + r2;
                atomicAdd(&gsum[gl], qs);
                atomicAdd(&gsq[gl], qq);
            }
        }
    }
    __syncthreads();
    if (stats && tid < 16) {
        atomicAdd(&stats[((size_t)b * GNG_ + mb * 16 + tid) * 2 + 0], gsum[tid]);
        atomicAdd(&stats[((size_t)b * GNG_ + mb * 16 + tid) * 2 + 1], gsq[tid]);
    }
}

// ------- conv3x3 via MFMA (split-bf16, implicit im2col). K split in 2 across blockIdx.y -------
__global__ __launch_bounds__(256) void k_conv3x3m(const ushort* __restrict__ awt_h, const ushort* __restrict__ awt_l,
                                                  const ushort* __restrict__ xh, const ushort* __restrict__ xl,
                                                  const float* __restrict__ bias,
                                                  float* __restrict__ om1, float* __restrict__ om2) {
    int nb = blockIdx.x;        // 144 pixel tiles of 64
    int ks = blockIdx.y;        // K-split half
    int b  = blockIdx.z;
    int n0 = nb * 64;
    __shared__ __align__(16) ushort Ah[256 * 32];
    __shared__ __align__(16) ushort Al[256 * 32];
    __shared__ __align__(16) ushort Bh[64 * 32];
    __shared__ __align__(16) ushort Bl[64 * 32];
    int tid = threadIdx.x;
    int lane = tid & 63, wv = tid >> 6;
    int mh = (wv >> 1) * 128;
    int nq = (wv & 1) * 32;
    int lr = lane & 31;
    int kg = lane >> 5;

    f32x16 acc[4] = {};

    int sn = tid >> 2, sch = tid & 3;
    int sp = n0 + sn;
    int spy = sp / W_, spx = sp - spy * W_;

    for (int q = ks * 36; q < ks * 36 + 36; ++q) {
        int tap = q >> 3, cb = q & 7;
        int dy = tap / 3 - 1, dx = tap % 3 - 1;
        const uint4* gah = (const uint4*)(awt_h + (size_t)q * 8192);
        const uint4* gal = (const uint4*)(awt_l + (size_t)q * 8192);
        uint4* sah = (uint4*)Ah; uint4* sal = (uint4*)Al;
        #pragma unroll
        for (int i = 0; i < 4; ++i) {
            int ci = i * 256 + tid;
            int m = ci >> 2, c4 = ci & 3;
            int sw = c4 ^ ((m >> 1) & 3);
            sah[m * 4 + sw] = gah[ci];
            sal[m * 4 + sw] = gal[ci];
        }
        {
            int y = spy + dy, x = spx + dx;
            uint4 vh = {0u, 0u, 0u, 0u}, vl = {0u, 0u, 0u, 0u};
            if ((unsigned)y < (unsigned)H_ && (unsigned)x < (unsigned)W_) {
                size_t sidx = (((size_t)(b * 8 + cb)) * HW_ + y * W_ + x) * 32 + sch * 8;
                vh = *(const uint4*)(xh + sidx);
                vl = *(const uint4*)(xl + sidx);
            }
            int sw = sch ^ ((sn >> 1) & 3);
            ((uint4*)Bh)[sn * 4 + sw] = vh;
            ((uint4*)Bl)[sn * 4 + sw] = vl;
        }
        __syncthreads();
        #pragma unroll
        for (int s = 0; s < 2; ++s) {
            int chnk = 2 * s + kg;
            int nn = nq + lr;
            int bby = nn * 64 + ((chnk ^ ((nn >> 1) & 3)) << 4);
            short8 bh = *(const short8*)((const char*)Bh + bby);
            short8 bl = *(const short8*)((const char*)Bl + bby);
            #pragma unroll
            for (int f = 0; f < 4; ++f) {
                int row = mh + f * 32 + lr;
                int aby = row * 64 + ((chnk ^ ((row >> 1) & 3)) << 4);
                short8 a_h = *(const short8*)((const char*)Ah + aby);
                short8 a_l = *(const short8*)((const char*)Al + aby);
                acc[f] = __builtin_amdgcn_mfma_f32_32x32x16_bf16(a_h, bh, acc[f], 0, 0, 0);
                acc[f] = __builtin_amdgcn_mfma_f32_32x32x16_bf16(a_h, bl, acc[f], 0, 0, 0);
                acc[f] = __builtin_amdgcn_mfma_f32_32x32x16_bf16(a_l, bh, acc[f], 0, 0, 0);
            }
        }
        __syncthreads();
    }
    float* outp = (ks ? om2 : om1) + (size_t)b * OMC_ * HW_;
    int pix = n0 + nq + lr;
    #pragma unroll
    for (int f = 0; f < 4; ++f) {
        #pragma unroll
        for (int r = 0; r < 16; ++r) {
            int m = mh + f * 32 + (r & 3) + 8 * (r >> 2) + 4 * kg;
            if (m < OMC_) {
                float v = acc[f][r] + (ks ? 0.f : bias[m]);
                outp[(size_t)m * HW_ + pix] = v;
            }
        }
    }
}

// ------- per-thread corner-weight + gather state for k_dcnm -------
struct GState {
    float4 w4;
    float4 t00a, t01a, t10a, t11a, t00b, t01b, t10b, t11b;
};

__device__ __forceinline__ void corner_gather(int q, int b, int pix, int hh, int ww, int sch,
                                              const float* __restrict__ om1, const float* __restrict__ om2,
                                              const float* __restrict__ upb, GState& st) {
    int g = q / 9, k = q - g * 9;
    size_t i_oy = ((size_t)b * OMC_ + g * 18 + 2 * k) * HW_ + pix;
    size_t i_mv = ((size_t)b * OMC_ + 144 + g * 9 + k) * HW_ + pix;
    float oy = om1[i_oy] + om2[i_oy];
    float ox = om1[i_oy + HW_] + om2[i_oy + HW_];
    float mv = om1[i_mv] + om2[i_mv];
    float m = 1.f / (1.f + expf(-mv));
    float pyf = oy + (float)(hh - 1 + k / 3);
    float pxf = ox + (float)(ww - 1 + k % 3);
    float y0f = floorf(pyf), x0f = floorf(pxf);
    int y0 = (int)y0f, x0 = (int)x0f;
    float fy = pyf - y0f, fx = pxf - x0f;
    float wy0 = (y0 >= 0 && y0 < H_) ? (1.f - fy) : 0.f;
    float wy1 = (y0 + 1 >= 0 && y0 + 1 < H_) ? fy : 0.f;
    float wx0 = (x0 >= 0 && x0 < W_) ? (1.f - fx) : 0.f;
    float wx1 = (x0 + 1 >= 0 && x0 + 1 < W_) ? fx : 0.f;
    st.w4.x = wy0 * wx0 * m; st.w4.y = wy0 * wx1 * m;
    st.w4.z = wy1 * wx0 * m; st.w4.w = wy1 * wx1 * m;
    int y0c = min(max(y0, 0), H_ - 1), y1c = min(max(y0 + 1, 0), H_ - 1);
    int x0c = min(max(x0, 0), W_ - 1), x1c = min(max(x0 + 1, 0), W_ - 1);
    size_t chof = (size_t)g * 32 + sch * 8;
    const float* p00 = upb + (size_t)(y0c * W_ + x0c) * 256 + chof;
    const float* p01 = upb + (size_t)(y0c * W_ + x1c) * 256 + chof;
    const float* p10 = upb + (size_t)(y1c * W_ + x0c) * 256 + chof;
    const float* p11 = upb + (size_t)(y1c * W_ + x1c) * 256 + chof;
    st.t00a = *(const float4*)p00; st.t00b = *(const float4*)(p00 + 4);
    st.t01a = *(const float4*)p01; st.t01b = *(const float4*)(p01 + 4);
    st.t10a = *(const float4*)p10; st.t10b = *(const float4*)(p10 + 4);
    st.t11a = *(const float4*)p11; st.t11b = *(const float4*)(p11 + 4);
}

// ------- modulated deformable conv via MFMA (split-bf16), K-split x2, prefetched pipeline -------
// grid (144 nb, 4 = mb|ks<<1, B). ks=0 -> raw partial to out0, ks=1 -> raw partial to pacc.
__global__ __launch_bounds__(256) void k_dcnm(const float* __restrict__ up_cl,
                                              const float* __restrict__ om1, const float* __restrict__ om2,
                                              const ushort* __restrict__ dwh, const ushort* __restrict__ dwl,
                                              float* __restrict__ out0, float* __restrict__ pacc) {
    int nb = blockIdx.x;
    int mb = blockIdx.y & 1;
    int ks = blockIdx.y >> 1;
    int b  = blockIdx.z;
    int n0 = nb * 64;
    __shared__ __align__(16) ushort Ah[128 * 32];
    __shared__ __align__(16) ushort Al[128 * 32];
    __shared__ __align__(16) ushort Bh[64 * 32];
    __shared__ __align__(16) ushort Bl[64 * 32];
    int tid = threadIdx.x;
    int lane = tid & 63, wv = tid >> 6;
    int mh = (wv >> 1) * 64;
    int nq = (wv & 1) * 32;
    int lr = lane & 31;
    int kg = lane >> 5;

    f32x16 acc[2] = {};
    int sn = tid >> 2, sch = tid & 3;
    const float* upb = up_cl + (size_t)b * HW_ * 256;

    // per-thread pixel for B-staging / corner compute
    int pix = n0 + sn;
    int hh = pix / W_, ww = pix - hh * W_;
    int q0 = ks * 36;

    GState st;
    uint4 aH0, aH1, aL0, aL1;     // prefetched A-tile (2 uint4 each of h,l)
    // ---- prologue: prefetch q0 ----
    {
        const uint4* gah = (const uint4*)(dwh + ((size_t)q0 * 256 + mb * 128) * 32);
        const uint4* gal = (const uint4*)(dwl + ((size_t)q0 * 256 + mb * 128) * 32);
        aH0 = gah[tid]; aH1 = gah[256 + tid];
        aL0 = gal[tid]; aL1 = gal[256 + tid];
        corner_gather(q0, b, pix, hh, ww, sch, om1, om2, upb, st);
    }

    for (int qi = 0; qi < 36; ++qi) {
        int q = q0 + qi;
        // ---- blend current gather -> hv/lv (consumes st) ----
        ushort hv[8], lv[8];
        {
            float4 w4 = st.w4;
            float v0 = w4.x * st.t00a.x + w4.y * st.t01a.x + w4.z * st.t10a.x + w4.w * st.t11a.x;
            float v1 = w4.x * st.t00a.y + w4.y * st.t01a.y + w4.z * st.t10a.y + w4.w * st.t11a.y;
            float v2 = w4.x * st.t00a.z + w4.y * st.t01a.z + w4.z * st.t10a.z + w4.w * st.t11a.z;
            float v3 = w4.x * st.t00a.w + w4.y * st.t01a.w + w4.z * st.t10a.w + w4.w * st.t11a.w;
            float v4 = w4.x * st.t00b.x + w4.y * st.t01b.x + w4.z * st.t10b.x + w4.w * st.t11b.x;
            float v5 = w4.x * st.t00b.y + w4.y * st.t01b.y + w4.z * st.t10b.y + w4.w * st.t11b.y;
            float v6 = w4.x * st.t00b.z + w4.y * st.t01b.z + w4.z * st.t10b.z + w4.w * st.t11b.z;
            float v7 = w4.x * st.t00b.w + w4.y * st.t01b.w + w4.z * st.t10b.w + w4.w * st.t11b.w;
            bf16split(v0, hv[0], lv[0]); bf16split(v1, hv[1], lv[1]);
            bf16split(v2, hv[2], lv[2]); bf16split(v3, hv[3], lv[3]);
            bf16split(v4, hv[4], lv[4]); bf16split(v5, hv[5], lv[5]);
            bf16split(v6, hv[6], lv[6]); bf16split(v7, hv[7], lv[7]);
        }
        __syncthreads();   // previous MFMA done reading LDS
        // ---- LDS writes: A from prefetched regs, B from hv/lv ----
        {
            uint4* sah = (uint4*)Ah; uint4* sal = (uint4*)Al;
            int m0i = tid >> 2, c40 = tid & 3;
            int sw0 = c40 ^ ((m0i >> 1) & 3);
            sah[m0i * 4 + sw0] = aH0; sal[m0i * 4 + sw0] = aL0;
            int ci1 = 256 + tid;
            int m1i = ci1 >> 2, c41 = ci1 & 3;
            int sw1 = c41 ^ ((m1i >> 1) & 3);
            sah[m1i * 4 + sw1] = aH1; sal[m1i * 4 + sw1] = aL1;
            int swb = sch ^ ((sn >> 1) & 3);
            ((uint4*)Bh)[sn * 4 + swb] = *(const uint4*)hv;
            ((uint4*)Bl)[sn * 4 + swb] = *(const uint4*)lv;
        }
        // ---- prefetch q+1 (loads in flight across MFMA) ----
        if (qi + 1 < 36) {
            int qn = q + 1;
            const uint4* gah = (const uint4*)(dwh + ((size_t)qn * 256 + mb * 128) * 32);
            const uint4* gal = (const uint4*)(dwl + ((size_t)qn * 256 + mb * 128) * 32);
            aH0 = gah[tid]; aH1 = gah[256 + tid];
            aL0 = gal[tid]; aL1 = gal[256 + tid];
            corner_gather(qn, b, pix, hh, ww, sch, om1, om2, upb, st);
        }
        __syncthreads();   // LDS writes visible
        // ---- MFMA: 2 k-subs of 16 ----
        #pragma unroll
        for (int s = 0; s < 2; ++s) {
            int chnk = 2 * s + kg;
            int nn = nq + lr;
            int bby = nn * 64 + ((chnk ^ ((nn >> 1) & 3)) << 4);
            short8 bh = *(const short8*)((const char*)Bh + bby);
            short8 bl = *(const short8*)((const char*)Bl + bby);
            #pragma unroll
            for (int f = 0; f < 2; ++f) {
                int row = mh + f * 32 + lr;
                int aby = row * 64 + ((chnk ^ ((row >> 1) & 3)) << 4);
                short8 a_h = *(const short8*)((const char*)Ah + aby);
                short8 a_l = *(const short8*)((const char*)Al + aby);
                acc[f] = __builtin_amdgcn_mfma_f32_32x32x16_bf16(a_h, bh, acc[f], 0, 0, 0);
                acc[f] = __builtin_amdgcn_mfma_f32_32x32x16_bf16(a_h, bl, acc[f], 0, 0, 0);
                acc[f] = __builtin_amdgcn_mfma_f32_32x32x16_bf16(a_l, bh, acc[f], 0, 0, 0);
            }
        }
        __syncthreads();
    }
    // ---- epilogue: store raw partial (bias/relu/arm deferred to k_dcncomb) ----
    int pixe = n0 + nq + lr;
    float* dst = (ks ? pacc : out0);
    #pragma unroll
    for (int f = 0; f < 2; ++f) {
        #pragma unroll
        for (int r = 0; r < 16; ++r) {
            int m = mb * 128 + mh + f * 32 + (r & 3) + 8 * (r >> 2) + 4 * kg;
            dst[((size_t)b * 256 + m) * HW_ + pixe] = acc[f][r];
        }
    }
}

// ------- combine K-split partials: out = relu(out0 + pacc + bias) + arm -------
__global__ __launch_bounds__(256) void k_dcncomb(float* __restrict__ out, const float* __restrict__ pacc,
                                                 const float* __restrict__ dcnb, const float* __restrict__ arm) {
    int bc = blockIdx.x;
    int c = bc & 255;
    float bi = dcnb[c];
    size_t base = (size_t)bc * HW_;
    const float4* pp = (const float4*)(pacc + base);
    const float4* ap = (const float4*)(arm + base);
    float4* op = (float4*)(out + base);
    for (int i = threadIdx.x; i < HW_ / 4; i += 256) {
        float4 o = op[i];
        float4 p = pp[i];
        float4 a = ap[i];
        o.x = fmaxf(o.x + p.x + bi, 0.f) + a.x;
        o.y = fmaxf(o.y + p.y + bi, 0.f) + a.y;
        o.z = fmaxf(o.z + p.z + bi, 0.f) + a.z;
        o.w = fmaxf(o.w + p.w + bi, 0.f) + a.w;
        op[i] = o;
    }
}

extern "C" void kernel_launch(void* const* d_in, const int* in_sizes, int n_in,
                              void* d_out, int out_size, void* d_ws, size_t ws_size,
                              hipStream_t stream) {
    const float* feat_l = (const float*)d_in[0];
    const float* feat_s = (const float*)d_in[1];
    const float* aw  = (const float*)d_in[2];
    const float* ab  = (const float*)d_in[3];
    const float* g1w = (const float*)d_in[4];
    const float* g1b = (const float*)d_in[5];
    const float* cw  = (const float*)d_in[6];
    const float* cb  = (const float*)d_in[7];
    const float* g2w = (const float*)d_in[8];
    const float* g2b = (const float*)d_in[9];
    const float* ow  = (const float*)d_in[10];
    const float* ob  = (const float*)d_in[11];
    const float* gow = (const float*)d_in[12];
    const float* gob = (const float*)d_in[13];
    const float* comw= (const float*)d_in[14];
    const float* comb= (const float*)d_in[15];
    const float* dcnw= (const float*)d_in[16];
    const float* dcnb= (const float*)d_in[17];
    float* out = (float*)d_out;
    float* ws = (float*)d_ws;

    // Workspace (~96.7 MB, proven envelope), stream-order-safe aliasing:
    //   xreg: conv#1 X -> conv#2a X -> conv#2b X -> conv3x3 X -> pacc (k_dcnm ks=1 partial)
    //   wtreg: c1,c2 -> awth/awtl -> dwh/dwl
    //   offf -> om1 ; up_cf -> om2
    size_t off = 0;
    float* up_cf = ws + off; off += (size_t)B_ * C_ * HW_;
    float* up_cl = ws + off; off += (size_t)B_ * C_ * HW_;
    float* arm   = ws + off; off += (size_t)B_ * C_ * HW_;
    float* offf  = ws + off; off += (size_t)B_ * C_ * HW_;
    float* wtreg = ws + off; off += (size_t)2304 * 256;           // 589824 floats
    float* xreg  = ws + off; off += (size_t)B_ * 8 * HW_ * 32;    // 4,718,592 floats
    float* pooled= ws + off; off += B_ * C_;
    float* atten = ws + off; off += B_ * C_;
    float* stats = ws + off; off += 4 * B_ * GNG_;
    float* stats_arm = stats;
    float* stats_off = stats + 2 * B_ * GNG_;

    // wtreg overlays (sequential lifetimes)
    ushort* c1h = (ushort*)wtreg;
    ushort* c1l = c1h + (size_t)8 * 256 * 32;
    ushort* c2h = c1l + (size_t)8 * 256 * 32;
    ushort* c2l = c2h + (size_t)16 * 256 * 32;
    ushort* awth = (ushort*)wtreg;                        // after conv1x1m#2b
    ushort* awtl = awth + (size_t)72 * 256 * 32;
    ushort* dwh  = (ushort*)wtreg;                        // after conv3x3m
    ushort* dwl  = dwh + (size_t)72 * 256 * 32;

    // xreg overlays (sequential lifetimes)
    ushort* xh = (ushort*)xreg;
    ushort* xl = xh + (size_t)B_ * 8 * HW_ * 32;
    float* pacc = xreg;                                   // after conv3x3m: B*C*HW floats = exact fit

    float* om1 = offf;    // alias: offf dead after k_prepxg
    float* om2 = up_cf;   // alias: up_cf dead after prepxs(up)

    hipMemsetAsync(stats, 0, 4 * B_ * GNG_ * sizeof(float), stream);
    k_pool<<<B_ * C_, 256, 0, stream>>>(feat_l, pooled);
    k_atten<<<B_, 256, 0, stream>>>(pooled, aw, ab, g1w, g1b, atten);
    k_up<<<B_ * C_, 256, 0, stream>>>(feat_s, up_cf);
    k_transpose<<<dim3(8, 288, B_), 256, 0, stream>>>(up_cf, up_cl);

    // conv#1: arm_raw = cw @ (feat_l * atten) + cb, GN stats
    k_prepcw<<<8, 256, 0, stream>>>(cw, 256, c1h, c1l);
    k_prepxs<<<dim3(144, 8, B_), 256, 0, stream>>>(feat_l, xh, xl, atten, 1.f);
    k_conv1x1m<<<dim3(144, 2, B_), 256, 0, stream>>>(c1h, c1l, xh, xl, cb, nullptr, arm, stats_arm);
    k_gnfin<<<1, 64, 0, stream>>>(stats_arm, 1.f / (8.f * HW_));
    k_gnapply<<<B_ * C_, 256, 0, stream>>>(arm, stats_arm, g2w, g2b);

    // conv#2 in two K-halves sharing one X buffer
    k_prepcw<<<16, 256, 0, stream>>>(ow, 512, c2h, c2l);
    k_prepxs<<<dim3(144, 8, B_), 256, 0, stream>>>(arm, xh, xl, nullptr, 1.f);
    k_conv1x1m<<<dim3(144, 2, B_), 256, 0, stream>>>(c2h, c2l, xh, xl, ob, nullptr, offf, nullptr);
    k_prepxs<<<dim3(144, 8, B_), 256, 0, stream>>>(up_cf, xh, xl, nullptr, 2.f);
    k_conv1x1m<<<dim3(144, 2, B_), 256, 0, stream>>>(c2h + (size_t)8 * 256 * 32, c2l + (size_t)8 * 256 * 32,
                                                     xh, xl, ob, offf, offf, stats_off);
    k_gnfin<<<1, 64, 0, stream>>>(stats_off, 1.f / (8.f * HW_));

    // conv3x3 (GN fused into X-prep)
    k_prepw<<<72, 256, 0, stream>>>(comw, awth, awtl);
    k_prepxg<<<dim3(144, 8, B_), 256, 0, stream>>>(offf, stats_off, gow, gob, xh, xl);
    k_conv3x3m<<<dim3(144, 2, B_), 256, 0, stream>>>(awth, awtl, xh, xl, comb, om1, om2);

    // deformable conv: K-split x2 with prefetch pipeline, then combine
    k_prepdw<<<72, 256, 0, stream>>>(dcnw, dwh, dwl);
    k_dcnm<<<dim3(144, 4, B_), 256, 0, stream>>>(up_cl, om1, om2, dwh, dwl, out, pacc);
    k_dcncomb<<<B_ * C_, 256, 0, stream>>>(out, pacc, dcnb, arm);
}